// Round 19
// baseline (970.372 us; speedup 1.0000x reference)
//
#include <hip/hip_runtime.h>
#include <stdint.h>

typedef unsigned short ush;
typedef unsigned int u32;
typedef __attribute__((ext_vector_type(8))) short short8;
typedef __attribute__((ext_vector_type(4))) float f32x4;
typedef __attribute__((ext_vector_type(2))) float f32x2;

#define DEVI static __device__ __forceinline__

constexpr int CC = 128, CH = 128;
constexpr int CS = 131072;           // H*W*Z per (n,c)
constexpr float BNEPS = 1e-5f;

DEVI ush f2bf(float f) {
  u32 u = __float_as_uint(f);
  u += 0x7FFF + ((u >> 16) & 1);     // RNE
  return (ush)(u >> 16);
}
DEVI float bf2f(ush h) { return __uint_as_float(((u32)h) << 16); }
DEVI float lo16(u32 u) { return __uint_as_float(u << 16); }
DEVI float hi16(u32 u) { return __uint_as_float(u & 0xFFFF0000u); }

DEVI float gelu_tanh(float v) {
  float y = 0.79788456f * (v + 0.044715f * v * v * v);
  float e = __expf(2.0f * y);
  return v * (1.0f - 1.0f / (e + 1.0f));
}

DEVI float wave_sum(float v) {
  v += __shfl_xor(v, 1);  v += __shfl_xor(v, 2);  v += __shfl_xor(v, 4);
  v += __shfl_xor(v, 8);  v += __shfl_xor(v, 16); v += __shfl_xor(v, 32);
  return v;
}

// packed acc update for z-split (v_pk_fma_f32 via fp-contract)
#define ACCZ2(A, P, K0, K1, K2, XV2, WP2) do {                                \
    if ((P) <= 3)             A[(P)][WP2]   += (K0) * (XV2);                  \
    if ((P) >= 1 && (P) <= 4) A[(P)-1][WP2] += (K1) * (XV2);                  \
    if ((P) >= 2)             A[(P)-2][WP2] += (K2) * (XV2);                  \
  } while (0)

template<int ZZ>
DEVI void conv_planes_bf(const ush* __restrict__ smb, int hh, int wt,
                         const float* __restrict__ lkc, const float* __restrict__ w5c,
                         const float* __restrict__ w3a, const float* __restrict__ w3b,
                         f32x2 (&a0)[4][2], f32x2 (&a1)[4][2],
                         f32x2 (&a2)[4][2], f32x2 (&a3)[4][2])
{
  constexpr int PLO = ZZ ? 0 : 1;
  constexpr int PHI = ZZ ? 5 : 6;
  #pragma unroll 1
  for (int dh = 0; dh < 7; ++dh) {
    const ush* smr = smb + (size_t)(hh + dh)*1088 + 4*wt;
    const bool b1on = (dh >= 1 && dh <= 5);
    const bool b2on = (dh & 1) != 0;
    const bool b3on = (dh == 0 || dh == 3 || dh == 6);
    #pragma unroll
    for (int p = PLO; p < PHI; ++p) {
      const int g = ZZ*4 + p - 1;
      const ush* q = smr + g*136;
      uint2 d0 = *(const uint2*)(q);
      uint2 d1 = *(const uint2*)(q + 4);
      uint2 d2 = *(const uint2*)(q + 8);
      float v[12] = {lo16(d0.x), hi16(d0.x), lo16(d0.y), hi16(d0.y),
                     lo16(d1.x), hi16(d1.x), lo16(d1.y), hi16(d1.y),
                     lo16(d2.x), hi16(d2.x), lo16(d2.y), hi16(d2.y)};
      #pragma unroll
      for (int dwi = 0; dwi < 7; ++dwi) {
        const float* cp = lkc + (dh*7 + dwi)*3;
        float k0 = cp[0], k1 = cp[1], k2 = cp[2];
        #pragma unroll
        for (int wp2 = 0; wp2 < 2; ++wp2) {
          f32x2 xv; xv.x = v[1 + 2*wp2 + dwi]; xv.y = v[2 + 2*wp2 + dwi];
          ACCZ2(a0, p, k0, k1, k2, xv, wp2);
        }
      }
      if (b1on) {
        #pragma unroll
        for (int dwi = 1; dwi <= 5; ++dwi) {
          const float* cp = w5c + ((dh-1)*5 + (dwi-1))*3;
          float k0 = cp[0], k1 = cp[1], k2 = cp[2];
          #pragma unroll
          for (int wp2 = 0; wp2 < 2; ++wp2) {
            f32x2 xv; xv.x = v[1 + 2*wp2 + dwi]; xv.y = v[2 + 2*wp2 + dwi];
            ACCZ2(a1, p, k0, k1, k2, xv, wp2);
          }
        }
      }
      if (b2on) {
        #pragma unroll
        for (int k = 0; k < 3; ++k) {
          const int dwi = 1 + 2*k;
          const float* cp = w3a + (((dh-1)>>1)*3 + k)*3;
          float k0 = cp[0], k1 = cp[1], k2 = cp[2];
          #pragma unroll
          for (int wp2 = 0; wp2 < 2; ++wp2) {
            f32x2 xv; xv.x = v[1 + 2*wp2 + dwi]; xv.y = v[2 + 2*wp2 + dwi];
            ACCZ2(a2, p, k0, k1, k2, xv, wp2);
          }
        }
      }
      if (b3on) {
        #pragma unroll
        for (int k = 0; k < 3; ++k) {
          const int dwi = 3*k;
          const float* cp = w3b + ((dh/3)*3 + k)*3;
          float k0 = cp[0], k1 = cp[1], k2 = cp[2];
          #pragma unroll
          for (int wp2 = 0; wp2 < 2; ++wp2) {
            f32x2 xv; xv.x = v[1 + 2*wp2 + dwi]; xv.y = v[2 + 2*wp2 + dwi];
            ACCZ2(a3, p, k0, k1, k2, xv, wp2);
          }
        }
      }
    }
  }
}

DEVI void acc_stats(const f32x2 (&a)[4][2], float& s, float& q) {
  #pragma unroll
  for (int z = 0; z < 4; ++z)
    #pragma unroll
    for (int wp2 = 0; wp2 < 2; ++wp2) {
      float e0 = a[z][wp2].x, e1 = a[z][wp2].y;
      s += e0; q = fmaf(e0, e0, q);
      s += e1; q = fmaf(e1, e1, q);
    }
}

DEVI void cross_stats(const f32x2 (&u)[4][2], const f32x2 (&w)[4][2], float& c) {
  #pragma unroll
  for (int z = 0; z < 4; ++z)
    #pragma unroll
    for (int wp2 = 0; wp2 < 2; ++wp2) {
      c = fmaf(u[z][wp2].x, w[z][wp2].x, c);
      c = fmaf(u[z][wp2].y, w[z][wp2].y, c);
    }
}

DEVI uint2 packz(const f32x2 (&a)[4][2], int wp) {
  const int h = wp >> 1, l = wp & 1;
  ush o0 = f2bf(a[0][h][l]), o1 = f2bf(a[1][h][l]);
  ush o2 = f2bf(a[2][h][l]), o3 = f2bf(a[3][h][l]);
  return make_uint2((u32)o0 | ((u32)o1 << 16), (u32)o2 | ((u32)o3 << 16));
}

// ---------------------------------------------------------------------------
// K1: 4-branch depthwise conv (once) -> bf16 branch outputs + 14 moments
// (4 sums, 4 self-dots, 6 cross-dots) so combined-BN stats are analytic.
// ---------------------------------------------------------------------------
__global__ __launch_bounds__(512) void k_conv4(
    const float* __restrict__ x, const float* __restrict__ lk_w,
    const float* __restrict__ dw5_w, const float* __restrict__ dw3a_w,
    const float* __restrict__ dw3b_w,
    ush* __restrict__ y0, ush* __restrict__ y1, ush* __restrict__ y2,
    ush* __restrict__ y3, float* __restrict__ part1)
{
  __shared__ __align__(16) ush smb[14*8*136];   // 30464B bf16 x tile
  __shared__ float red[8][14];
  const int hb = blockIdx.x, c = blockIdx.y, n = blockIdx.z, tid = threadIdx.x;
  const float* xc = x + ((size_t)(n*CC + c))*CS;
  #pragma unroll
  for (int i = 0; i < 7; ++i) {
    int idx = i*512 + tid;
    int row = idx >> 8, r4 = idx & 255;
    int w = r4 >> 1, zh = r4 & 1;
    int hin = hb*8 - 3 + row;
    float4 val = make_float4(0.f,0.f,0.f,0.f);
    if (hin >= 0 && hin < CH) val = *(const float4*)(xc + (size_t)hin*1024 + w*8 + zh*4);
    ush* base = smb + (row*8 + zh*4)*136 + 4 + w;
    base[0]   = f2bf(val.x);
    base[136] = f2bf(val.y);
    base[272] = f2bf(val.z);
    base[408] = f2bf(val.w);
  }
  for (int idx = tid; idx < 896; idx += 512) {   // zero w-halo: pw {0..3, 132..135}
    int row = idx >> 6, rem = idx & 63;
    int z = rem >> 3, col = rem & 7;
    int pw = (col < 4) ? col : (128 + col);
    smb[(row*8 + z)*136 + pw] = 0;
  }
  __syncthreads();

  const int wt = tid & 31, hh = (tid >> 5) & 7, zz = tid >> 8;
  f32x2 a0[4][2] = {}, a1[4][2] = {}, a2[4][2] = {}, a3[4][2] = {};
  if (zz == 0)
    conv_planes_bf<0>(smb, hh, wt, lk_w + c*147, dw5_w + c*75, dw3a_w + c*27, dw3b_w + c*27,
                      a0, a1, a2, a3);
  else
    conv_planes_bf<1>(smb, hh, wt, lk_w + c*147, dw5_w + c*75, dw3a_w + c*27, dw3b_w + c*27,
                      a0, a1, a2, a3);

  float s0=0,q0=0,s1=0,q1=0,s2=0,q2=0,s3=0,q3=0;
  acc_stats(a0, s0, q0); acc_stats(a1, s1, q1);
  acc_stats(a2, s2, q2); acc_stats(a3, s3, q3);
  float c01=0,c02=0,c03=0,c12=0,c13=0,c23=0;
  cross_stats(a0, a1, c01); cross_stats(a0, a2, c02); cross_stats(a0, a3, c03);
  cross_stats(a1, a2, c12); cross_stats(a1, a3, c13); cross_stats(a2, a3, c23);

  // ---- coalesced store via LDS exchange: 1 branch (16KB) per round ----
  char* exch = (char*)smb;           // smb dead; 16KB used
  const int hbase = hb*8;
  const size_t nbase = ((size_t)(n*CC + c))*CS;
  const int row_r = tid >> 6, j_r = tid & 63;
  const int wt_s = j_r >> 1, p0 = (j_r & 1)*2;
  const int sxor = (wt_s & 7) << 3;
  #pragma unroll
  for (int rnd = 0; rnd < 4; ++rnd) {
    const f32x2 (&aa)[4][2] = (rnd == 0) ? a0 : (rnd == 1) ? a1 : (rnd == 2) ? a2 : a3;
    ush* yb = (rnd == 0) ? y0 : (rnd == 1) ? y1 : (rnd == 2) ? y2 : y3;
    __syncthreads();                 // previous round's reads (or conv reads) done
    {
      const int wbyte = hh*2048 + wt*64;
      #pragma unroll
      for (int wp = 0; wp < 4; ++wp) {
        int swz = (wp*16 + zz*8) ^ ((wt & 7) << 3);
        *(uint2*)(exch + wbyte + swz) = packz(aa, wp);
      }
    }
    __syncthreads();
    {
      const char* src = exch + row_r*2048 + wt_s*64;
      uint2 e0 = *(const uint2*)(src + ((p0*16 + 0)  ^ sxor));
      uint2 e1 = *(const uint2*)(src + ((p0*16 + 8)  ^ sxor));
      uint2 e2 = *(const uint2*)(src + ((p0*16 + 16) ^ sxor));
      uint2 e3 = *(const uint2*)(src + ((p0*16 + 24) ^ sxor));
      ush* dst = yb + nbase + (size_t)(hbase + row_r)*1024 + j_r*16;
      *(uint4*)(dst)     = make_uint4(e0.x, e0.y, e1.x, e1.y);
      *(uint4*)(dst + 8) = make_uint4(e2.x, e2.y, e3.x, e3.y);
    }
  }

  float vals[14] = {s0,s1,s2,s3,q0,q1,q2,q3,c01,c02,c03,c12,c13,c23};
  #pragma unroll
  for (int jj = 0; jj < 14; ++jj) vals[jj] = wave_sum(vals[jj]);
  const int wid = tid >> 6, lane = tid & 63;
  if (lane == 0) {
    #pragma unroll
    for (int jj = 0; jj < 14; ++jj) red[wid][jj] = vals[jj];
  }
  __syncthreads();
  if (tid < 14) {
    float s = 0.f;
    #pragma unroll
    for (int w2 = 0; w2 < 8; ++w2) s += red[w2][tid];
    part1[(((size_t)n*CC + c)*16 + hb)*16 + tid] = s;
  }
}

// ---------------------------------------------------------------------------
// K2: merged stats: per-branch BN -> svec/T; analytic combined BN; SE -> ABuf
// ---------------------------------------------------------------------------
__global__ __launch_bounds__(512) void k_stats(
    const float* __restrict__ part1,
    const float* bn0_w, const float* bn0_b, const float* dbn1_w, const float* dbn1_b,
    const float* dbn2_w, const float* dbn2_b, const float* dbn3_w, const float* dbn3_b,
    const float* nrm_w, const float* nrm_b,
    const float* se_dw, const float* se_db, const float* se_uw, const float* se_ub,
    float* __restrict__ svec, float* __restrict__ Tbuf, float* __restrict__ ABuf)
{
  __shared__ float sA[4][128], tA[4][128], QA[4][128], S0A[4][128], SfA[4][128];
  __shared__ float pmA[2][128], hA[2][32], alA[128], beA[128];
  const int tid = threadIdx.x;
  {
    int c = tid >> 2, b = tid & 3;
    float s_f = 0.f, s_0 = 0.f, q = 0.f;
    for (int n = 0; n < 2; n++)
      for (int hb = 0; hb < 16; hb++) {
        const float* p = part1 + (((size_t)n*CC + c)*16 + hb)*16;
        float v = p[b];
        s_f += v; if (n == 0) s_0 += v;
        q += p[4 + b];
      }
    float mean = s_f * (1.f/262144.f);
    float var  = q * (1.f/262144.f) - mean*mean;
    float g, bb;
    if (b == 0)      { g = bn0_w[c];  bb = bn0_b[c];  }
    else if (b == 1) { g = dbn1_w[c]; bb = dbn1_b[c]; }
    else if (b == 2) { g = dbn2_w[c]; bb = dbn2_b[c]; }
    else             { g = dbn3_w[c]; bb = dbn3_b[c]; }
    float sc = g * rsqrtf(var + BNEPS);
    svec[c*4 + b] = sc;
    sA[b][c] = sc;
    tA[b][c] = bb - mean * sc;
    QA[b][c] = q; S0A[b][c] = s_0; SfA[b][c] = s_f;
  }
  __syncthreads();
  if (tid < 128) {
    int c = tid;
    float cr[6] = {0,0,0,0,0,0};
    for (int n = 0; n < 2; n++)
      for (int hb = 0; hb < 16; hb++) {
        const float* p = part1 + (((size_t)n*CC + c)*16 + hb)*16 + 8;
        #pragma unroll
        for (int k = 0; k < 6; k++) cr[k] += p[k];
      }
    float s0 = sA[0][c], s1 = sA[1][c], s2 = sA[2][c], s3 = sA[3][c];
    float T = tA[0][c] + tA[1][c] + tA[2][c] + tA[3][c];
    Tbuf[c] = T;
    float wf = s0*SfA[0][c] + s1*SfA[1][c] + s2*SfA[2][c] + s3*SfA[3][c];
    float w0 = s0*S0A[0][c] + s1*S0A[1][c] + s2*S0A[2][c] + s3*S0A[3][c];
    float sum_full = wf + 262144.f*T;
    float sumsq = s0*s0*QA[0][c] + s1*s1*QA[1][c] + s2*s2*QA[2][c] + s3*s3*QA[3][c]
                + 2.f*(s0*s1*cr[0] + s0*s2*cr[1] + s0*s3*cr[2]
                     + s1*s2*cr[3] + s1*s3*cr[4] + s2*s3*cr[5])
                + 2.f*T*wf + 262144.f*T*T;
    float m   = sum_full * (1.f/262144.f);
    float var = sumsq * (1.f/262144.f) - m*m;
    float inv = rsqrtf(var + BNEPS);
    float al = nrm_w[c]*inv;
    float be = nrm_b[c] - m*al;
    alA[c] = al; beA[c] = be;
    float sum_n0 = w0 + 131072.f*T;
    float sum_n1 = (wf - w0) + 131072.f*T;
    pmA[0][c] = (sum_n0*(1.f/131072.f) - m)*al + be;
    pmA[1][c] = (sum_n1*(1.f/131072.f) - m)*al + be;
  }
  __syncthreads();
  if (tid < 64) {
    int n = tid >> 5, i = tid & 31;
    float h = se_db[i];
    for (int c2 = 0; c2 < 128; c2++) h += pmA[n][c2]*se_dw[i*128 + c2];
    hA[n][i] = fmaxf(h, 0.f);
  }
  __syncthreads();
  if (tid < 256) {
    int n = tid >> 7, c = tid & 127;
    float sse = se_ub[c];
    #pragma unroll
    for (int i = 0; i < 32; i++) sse += hA[n][i]*se_uw[c*32 + i];
    ABuf[(n*128 + c)*2 + 0] = alA[c]*sse;
    ABuf[(n*128 + c)*2 + 1] = beA[c]*sse;
  }
}

// ---------------------------------------------------------------------------
// K5: fold A into w1 (bf16, [n][f][c]) and B into beta[n][f]
// ---------------------------------------------------------------------------
__global__ __launch_bounds__(512) void k_w1prep(
    const float* __restrict__ w1, const float* __restrict__ b1,
    const float* __restrict__ ABuf, ush* __restrict__ w1t, float* __restrict__ beta)
{
  const int n = blockIdx.x, tid = threadIdx.x;
  __shared__ float Asc[128], Bsc[128];
  if (tid < 128) { Asc[tid] = ABuf[(n*128 + tid)*2]; Bsc[tid] = ABuf[(n*128 + tid)*2 + 1]; }
  __syncthreads();
  for (int i = tid; i < 512*128; i += 512) {     // write-contiguous
    int f = i >> 7, cc = i & 127;
    w1t[((size_t)n*512 + f)*128 + cc] = f2bf(w1[cc*512 + f] * Asc[cc]);
  }
  {
    int f = tid;
    float s = b1[f];
    for (int cc = 0; cc < 128; cc++) s += Bsc[cc]*w1[cc*512 + f];
    beta[n*512 + f] = s;
  }
}

// ---------------------------------------------------------------------------
// K7: GEMM1 t[n,s,f] = gelu( y @ w1t_n^T + beta ); A-tile combined on the fly
// from the 4 branch buffers (svec/T) and transposed NCS->NSC via Bl scratch
// (k_combine's validated granule-swizzle), then placed MFMA-swizzled in Al.
// ---------------------------------------------------------------------------
__global__ __launch_bounds__(256) void k_gemm1(
    const ush* __restrict__ y0, const ush* __restrict__ y1,
    const ush* __restrict__ y2, const ush* __restrict__ y3,
    const float* __restrict__ svec, const float* __restrict__ Tb,
    const ush* __restrict__ w1t, const float* __restrict__ beta,
    ush* __restrict__ tbuf, float* __restrict__ grnp)
{
  __shared__ __align__(16) ush Al[16384];
  __shared__ __align__(16) ush Bl[16384];
  const int l = blockIdx.x, tid = threadIdx.x;
  const int mt = (l & 7) | ((l >> 6) << 3);
  const int r  = (l >> 3) & 7;
  const int n  = r >> 2, ft = r & 3;
  const ush* Bb = w1t + ((size_t)n*512 + (size_t)ft*128) * 128;

  // step 1: combine branches into Bl (granule-swizzled transpose scratch)
  #pragma unroll
  for (int i = 0; i < 8; i++) {
    int g = i*256 + tid;
    int cc = g >> 4, s8 = g & 15;
    size_t off = ((size_t)(n*CC + cc))*CS + (size_t)mt*128 + s8*8;
    uint4 v0 = *(const uint4*)(y0 + off);
    uint4 v1 = *(const uint4*)(y1 + off);
    uint4 v2 = *(const uint4*)(y2 + off);
    uint4 v3 = *(const uint4*)(y3 + off);
    float4 sv = *(const float4*)(svec + cc*4);
    float Tc = Tb[cc];
    union { uint4 q; ush e[8]; } u0, u1, u2, u3, uo;
    u0.q = v0; u1.q = v1; u2.q = v2; u3.q = v3;
    #pragma unroll
    for (int j = 0; j < 8; j++) {
      float y = sv.x*bf2f(u0.e[j]) + sv.y*bf2f(u1.e[j])
              + sv.z*bf2f(u2.e[j]) + sv.w*bf2f(u3.e[j]) + Tc;
      uo.e[j] = f2bf(y);
    }
    #pragma unroll
    for (int j = 0; j < 8; j++) {
      int s_l = s8*8 + j;
      int gran = s_l*16 + ((cc >> 3) ^ (s8 & 7));
      Bl[gran*8 + (cc & 7)] = uo.e[j];
    }
  }
  __syncthreads();
  // step 2: read NSC 16B chunks out of the granule layout
  uint4 areg[8];
  #pragma unroll
  for (int i = 0; i < 8; i++) {
    int idx = i*256 + tid;
    int s_l = idx >> 4, gc = idx & 15;
    int gran = s_l*16 + (gc ^ ((s_l >> 3) & 7));
    areg[i] = *(const uint4*)&Bl[gran*8];
  }
  __syncthreads();
  // step 3: place A MFMA-swizzled in Al; stage B into Bl
  #pragma unroll
  for (int i = 0; i < 8; i++) {
    int idx = i*256 + tid;
    int rr = idx >> 4, cg = idx & 15;
    *(uint4*)&Al[rr*128 + ((cg ^ (rr & 7))*8)] = areg[i];
    *(uint4*)&Bl[rr*128 + ((cg ^ (rr & 7))*8)] = *(const uint4*)(Bb + (size_t)idx*8);
  }
  __syncthreads();

  const int wid = tid >> 6, lane = tid & 63;
  const int wm = wid >> 1, wn = wid & 1;
  const int lr = lane & 15, lk = lane >> 4;
  f32x4 acc[4][4] = {};
  #pragma unroll
  for (int kk = 0; kk < 4; kk++) {
    short8 af[4], bfr[4];
    #pragma unroll
    for (int mf = 0; mf < 4; mf++) {
      int row = wm*64 + mf*16 + lr;
      int cg = (kk*4 + lk) ^ (row & 7);
      af[mf] = *(const short8*)&Al[row*128 + cg*8];
    }
    #pragma unroll
    for (int nf = 0; nf < 4; nf++) {
      int row = wn*64 + nf*16 + lr;
      int cg = (kk*4 + lk) ^ (row & 7);
      bfr[nf] = *(const short8*)&Bl[row*128 + cg*8];
    }
    #pragma unroll
    for (int mf = 0; mf < 4; mf++)
      #pragma unroll
      for (int nf = 0; nf < 4; nf++)
        acc[mf][nf] = __builtin_amdgcn_mfma_f32_16x16x32_bf16(af[mf], bfr[nf], acc[mf][nf], 0, 0, 0);
  }

  float bt[4];
  #pragma unroll
  for (int nf = 0; nf < 4; nf++) bt[nf] = beta[n*512 + ft*128 + wn*64 + nf*16 + lr];
  float sq[4] = {0.f,0.f,0.f,0.f};
  #pragma unroll
  for (int mf = 0; mf < 4; mf++)
    #pragma unroll
    for (int nf = 0; nf < 4; nf++)
      #pragma unroll
      for (int rg = 0; rg < 4; rg++) {
        float g = gelu_tanh(acc[mf][nf][rg] + bt[nf]);
        sq[nf] += g*g;
        acc[mf][nf][rg] = g;
      }
  __syncthreads();
  float* grnl = (float*)Al;
  #pragma unroll
  for (int nf = 0; nf < 4; nf++) {
    float v = sq[nf];
    v += __shfl_xor(v, 16); v += __shfl_xor(v, 32);
    if (lane < 16) grnl[(wn*64 + nf*16 + lane)*2 + wm] = v;
  }
  #pragma unroll
  for (int mf = 0; mf < 4; mf++)
    #pragma unroll
    for (int nf = 0; nf < 4; nf++)
      #pragma unroll
      for (int rg = 0; rg < 4; rg++) {
        int ml = wm*64 + mf*16 + lk*4 + rg;
        int fl = wn*64 + nf*16 + lr;
        Bl[ml*128 + (fl ^ (((ml >> 2) & 3) << 4))] = f2bf(acc[mf][nf][rg]);
      }
  __syncthreads();
  #pragma unroll
  for (int i = 0; i < 8; i++) {
    int idx = i*256 + tid;
    int m = idx >> 4, gc = idx & 15;
    uint4 v = *(const uint4*)&Bl[m*128 + ((gc ^ (((m >> 2) & 3) << 1))*8)];
    *(uint4*)(tbuf + ((size_t)n*CS + (size_t)mt*128 + m)*512 + ft*128 + gc*8) = v;
  }
  if (tid < 128) grnp[(size_t)mt*1024 + n*512 + ft*128 + tid] = grnl[tid*2] + grnl[tid*2+1];
}

// K8a: GRN partial reduce over mt (64 blocks)
__global__ __launch_bounds__(256) void k_grn1(
    const float* __restrict__ grnp, float* __restrict__ gpart)
{
  const int j = blockIdx.x, tid = threadIdx.x;
  float acc[4] = {0.f, 0.f, 0.f, 0.f};
  for (int i = 0; i < 16; ++i) {
    const float* p = grnp + (size_t)(j*16 + i)*1024;
    #pragma unroll
    for (int ch = 0; ch < 4; ++ch) acc[ch] += p[ch*256 + tid];
  }
  #pragma unroll
  for (int ch = 0; ch < 4; ++ch) gpart[(size_t)j*1024 + ch*256 + tid] = acc[ch];
}

// K8b: GRN final: Gx -> Nx -> a[n][f] = grn_g*Nx + 1
__global__ __launch_bounds__(1024) void k_grn2(
    const float* __restrict__ gpart, const float* __restrict__ grn_g, float* __restrict__ aBuf)
{
  __shared__ float wsum[16], gm[2];
  const int tid = threadIdx.x;
  float s = 0.f;
  for (int j = 0; j < 64; ++j) s += gpart[(size_t)j*1024 + tid];
  float Gx = sqrtf(s);
  float v = wave_sum(Gx);
  if ((tid & 63) == 0) wsum[tid >> 6] = v;
  __syncthreads();
  if (tid < 2) {
    float m = 0.f;
    #pragma unroll
    for (int w2 = 0; w2 < 8; w2++) m += wsum[tid*8 + w2];
    gm[tid] = m * (1.f/512.f) + 1e-6f;
  }
  __syncthreads();
  int n = tid >> 9, f = tid & 511;
  aBuf[tid] = grn_g[f] * (Gx / gm[n]) + 1.f;
}

// K9: w2t[n][co][f] = w2[f][co]*a[n][f]  (bf16)  + cvec (n==0 block)
__global__ __launch_bounds__(512) void k_w2prep(
    const float* __restrict__ w2, const float* __restrict__ aBuf,
    const float* __restrict__ grn_b, ush* __restrict__ w2t, float* __restrict__ cvec)
{
  const int n = blockIdx.x, tid = threadIdx.x;
  for (int i = tid; i < 128*512; i += 512) {     // write-contiguous
    int co = i >> 9, f = i & 511;
    w2t[((size_t)n*128 + co)*512 + f] = f2bf(w2[(size_t)f*128 + co] * aBuf[n*512 + f]);
  }
  if (n == 0) {
    __shared__ float cs[4][128];
    int co = tid & 127, qh = tid >> 7;
    float s = 0.f;
    for (int f = qh*128; f < qh*128 + 128; ++f) s += grn_b[f]*w2[(size_t)f*128 + co];
    cs[qh][co] = s;
    __syncthreads();
    if (tid < 128) cvec[tid] = cs[0][tid] + cs[1][tid] + cs[2][tid] + cs[3][tid];
  }
}

// ---------------------------------------------------------------------------
// K11: GEMM2  u (NCS layout) = t @ w2t_n^T + cvec, bf16 out + post-BN partials
// ---------------------------------------------------------------------------
__global__ __launch_bounds__(256) void k_gemm2(
    const ush* __restrict__ tbuf, const ush* __restrict__ w2t,
    const float* __restrict__ cvec, ush* __restrict__ u, float* __restrict__ upart)
{
  __shared__ __align__(16) ush Al[16384];
  __shared__ __align__(16) ush Bl[16384];
  const int mt = blockIdx.x, n = blockIdx.y, tid = threadIdx.x;
  const int wid = tid >> 6, lane = tid & 63;
  const int wm = wid >> 1, wn = wid & 1;
  const int lr = lane & 15, lk = lane >> 4;
  f32x4 acc[4][4] = {};
  #pragma unroll 1
  for (int kb = 0; kb < 4; kb++) {
    if (kb) __syncthreads();
    #pragma unroll
    for (int i = 0; i < 8; i++) {
      int g = i*256 + tid;
      int rr = g >> 4, cg = g & 15;
      *(uint4*)&Al[rr*128 + ((cg ^ (rr & 7))*8)] =
        *(const uint4*)(tbuf + ((size_t)n*CS + (size_t)mt*128 + rr)*512 + kb*128 + cg*8);
      *(uint4*)&Bl[rr*128 + ((cg ^ (rr & 7))*8)] =
        *(const uint4*)(w2t + ((size_t)n*128 + rr)*512 + kb*128 + cg*8);
    }
    __syncthreads();
    #pragma unroll
    for (int kk = 0; kk < 4; kk++) {
      short8 af[4], bfr[4];
      #pragma unroll
      for (int mf = 0; mf < 4; mf++) {
        int row = wm*64 + mf*16 + lr;
        int cg = (kk*4 + lk) ^ (row & 7);
        af[mf] = *(const short8*)&Al[row*128 + cg*8];
      }
      #pragma unroll
      for (int nf = 0; nf < 4; nf++) {
        int row = wn*64 + nf*16 + lr;
        int cg = (kk*4 + lk) ^ (row & 7);
        bfr[nf] = *(const short8*)&Bl[row*128 + cg*8];
      }
      #pragma unroll
      for (int mf = 0; mf < 4; mf++)
        #pragma unroll
        for (int nf = 0; nf < 4; nf++)
          acc[mf][nf] = __builtin_amdgcn_mfma_f32_16x16x32_bf16(af[mf], bfr[nf], acc[mf][nf], 0, 0, 0);
    }
  }
  float cv[4];
  #pragma unroll
  for (int nf = 0; nf < 4; nf++) cv[nf] = cvec[wn*64 + nf*16 + lr];
  float su[4] = {0,0,0,0}, sq[4] = {0,0,0,0};
  #pragma unroll
  for (int mf = 0; mf < 4; mf++)
    #pragma unroll
    for (int nf = 0; nf < 4; nf++)
      #pragma unroll
      for (int rg = 0; rg < 4; rg++) {
        float v = acc[mf][nf][rg] + cv[nf];
        su[nf] += v; sq[nf] += v*v;
        acc[mf][nf][rg] = v;
      }
  __syncthreads();
  float* stl = (float*)Al;
  #pragma unroll
  for (int nf = 0; nf < 4; nf++) {
    float a = su[nf]; a += __shfl_xor(a, 16); a += __shfl_xor(a, 32);
    float b = sq[nf]; b += __shfl_xor(b, 16); b += __shfl_xor(b, 32);
    if (lane < 16) {
      stl[((wn*64 + nf*16 + lane)*2 + wm)*2 + 0] = a;
      stl[((wn*64 + nf*16 + lane)*2 + wm)*2 + 1] = b;
    }
  }
  // transposed scatter: Bl row = c index (fl), col = s index (ml)
  #pragma unroll
  for (int mf = 0; mf < 4; mf++)
    #pragma unroll
    for (int nf = 0; nf < 4; nf++)
      #pragma unroll
      for (int rg = 0; rg < 4; rg++) {
        int ml = wm*64 + mf*16 + lk*4 + rg;
        int fl = wn*64 + nf*16 + lr;
        Bl[fl*128 + (ml ^ (((fl >> 2) & 3) << 4))] = f2bf(acc[mf][nf][rg]);
      }
  __syncthreads();
  #pragma unroll
  for (int i = 0; i < 8; i++) {
    int idx = i*256 + tid;
    int cr = idx >> 4, gm = idx & 15;
    uint4 v = *(const uint4*)&Bl[cr*128 + ((gm ^ (((cr >> 2) & 3) << 1))*8)];
    *(uint4*)(u + ((size_t)(n*CC + cr))*CS + (size_t)mt*128 + gm*8) = v;
  }
  if (tid < 128) {
    float s = stl[(tid*2 + 0)*2 + 0] + stl[(tid*2 + 1)*2 + 0];
    float q = stl[(tid*2 + 0)*2 + 1] + stl[(tid*2 + 1)*2 + 1];
    upart[((size_t)(n*1024 + mt)*128 + tid)*2 + 0] = s;
    upart[((size_t)(n*1024 + mt)*128 + tid)*2 + 1] = q;
  }
}

// K12: post-BN stats -> P,Q per channel
__global__ __launch_bounds__(256) void k_pbn(
    const float* __restrict__ upart, const float* pbn_w, const float* pbn_b,
    const float* ls_g, float* __restrict__ PQ)
{
  __shared__ float rs[4], rq[4];
  const int c = blockIdx.x, tid = threadIdx.x;
  float s = 0.f, q = 0.f;
  for (int mtg = tid; mtg < 2048; mtg += 256) {
    s += upart[((size_t)mtg*128 + c)*2 + 0];
    q += upart[((size_t)mtg*128 + c)*2 + 1];
  }
  s = wave_sum(s); q = wave_sum(q);
  if ((tid & 63) == 0) { rs[tid >> 6] = s; rq[tid >> 6] = q; }
  __syncthreads();
  if (tid == 0) {
    float S = rs[0]+rs[1]+rs[2]+rs[3];
    float Qq = rq[0]+rq[1]+rq[2]+rq[3];
    float m = S*(1.f/262144.f);
    float var = Qq*(1.f/262144.f) - m*m;
    float inv = rsqrtf(var + BNEPS);
    PQ[c*2 + 0] = ls_g[c]*pbn_w[c]*inv;
    PQ[c*2 + 1] = ls_g[c]*(pbn_b[c] - m*inv*pbn_w[c]);
  }
}

// K13: out[n,c,s] = x + u_ncs*P[c] + Q[c]  — the ONLY writer of d_out
__global__ __launch_bounds__(256) void k_final(
    const ush* __restrict__ u, const float* __restrict__ x,
    const float* __restrict__ PQ, float* __restrict__ out)
{
  size_t e = ((size_t)blockIdx.x*256 + threadIdx.x)*4;
  int c = (int)((e >> 17) & 127);
  float P = PQ[c*2], Q = PQ[c*2 + 1];
  uint2 uv = *(const uint2*)(u + e);
  float4 xv = *(const float4*)(x + e);
  float4 o;
  o.x = fmaf(bf2f((ush)(uv.x & 0xffff)), P, xv.x + Q);
  o.y = fmaf(bf2f((ush)(uv.x >> 16)),   P, xv.y + Q);
  o.z = fmaf(bf2f((ush)(uv.y & 0xffff)), P, xv.z + Q);
  o.w = fmaf(bf2f((ush)(uv.y >> 16)),   P, xv.w + Q);
  *(float4*)(out + e) = o;
}

// ---------------------------------------------------------------------------
extern "C" void kernel_launch(void* const* d_in, const int* in_sizes, int n_in,
                              void* d_out, int out_size, void* d_ws, size_t ws_size,
                              hipStream_t stream)
{
  (void)in_sizes; (void)n_in; (void)out_size; (void)ws_size;
  const float* x      = (const float*)d_in[0];
  const float* lk_w   = (const float*)d_in[1];
  const float* bn0_w  = (const float*)d_in[2];
  const float* bn0_b  = (const float*)d_in[3];
  const float* dw5_w  = (const float*)d_in[4];
  const float* dbn1_w = (const float*)d_in[5];
  const float* dbn1_b = (const float*)d_in[6];
  const float* dw3a_w = (const float*)d_in[7];
  const float* dbn2_w = (const float*)d_in[8];
  const float* dbn2_b = (const float*)d_in[9];
  const float* dw3b_w = (const float*)d_in[10];
  const float* dbn3_w = (const float*)d_in[11];
  const float* dbn3_b = (const float*)d_in[12];
  const float* nrm_w  = (const float*)d_in[13];
  const float* nrm_b  = (const float*)d_in[14];
  const float* se_dw  = (const float*)d_in[15];
  const float* se_db  = (const float*)d_in[16];
  const float* se_uw  = (const float*)d_in[17];
  const float* se_ub  = (const float*)d_in[18];
  const float* w1     = (const float*)d_in[19];
  const float* b1     = (const float*)d_in[20];
  const float* grn_g  = (const float*)d_in[21];
  const float* grn_b  = (const float*)d_in[22];
  const float* w2     = (const float*)d_in[23];
  const float* pbn_w  = (const float*)d_in[24];
  const float* pbn_b  = (const float*)d_in[25];
  const float* ls_g   = (const float*)d_in[26];

  char* w = (char*)d_ws;
  size_t cur = 0;
  auto take = [&](size_t b) { size_t r = cur; cur += (b + 255) & ~(size_t)255; return r; };
  ush*   tbuf  = (ush*)  (w + take((size_t)2*CS*512*2));   // 268.4MB; y0..y3 alias (exact fit)
  ush*   ycl_u = (ush*)  (w + take((size_t)2*CS*128*2));   // 67.1MB; u
  float* partU = (float*)(w + take((size_t)2*512*128*2*4));// part1 (16/slot)
  float* svec  = (float*)(w + take(128*4*4));
  float* TbufA = (float*)(w + take(128*4));
  float* ABuf  = (float*)(w + take(2*128*2*4));
  ush*   w1t   = (ush*)  (w + take(2*512*128*2));
  float* beta  = (float*)(w + take(2*512*4));
  float* grnpU = (float*)(w + take((size_t)1024*1024*4));  // grnp then upart
  float* gpart = (float*)(w + take((size_t)64*1024*4));
  float* aBuf  = (float*)(w + take(2*512*4));
  ush*   w2t   = (ush*)  (w + take(2*128*512*2));
  float* cvec  = (float*)(w + take(128*4));
  float* PQ    = (float*)(w + take(128*2*4));

  const size_t YSZ = (size_t)2*CC*CS;         // 33.5M ush per branch buffer
  ush*   y0    = tbuf;
  ush*   y1    = tbuf + YSZ;
  ush*   y2    = tbuf + 2*YSZ;
  ush*   y3    = tbuf + 3*YSZ;
  ush*   u_buf = ycl_u;
  float* part1 = partU;
  float* grnp  = grnpU;
  float* upart = grnpU;
  float* outp  = (float*)d_out;

  k_conv4<<<dim3(16,128,2), 512, 0, stream>>>(x, lk_w, dw5_w, dw3a_w, dw3b_w,
                                              y0, y1, y2, y3, part1);
  k_stats<<<1, 512, 0, stream>>>(part1, bn0_w, bn0_b, dbn1_w, dbn1_b,
                                 dbn2_w, dbn2_b, dbn3_w, dbn3_b,
                                 nrm_w, nrm_b, se_dw, se_db, se_uw, se_ub,
                                 svec, TbufA, ABuf);
  k_w1prep<<<2, 512, 0, stream>>>(w1, b1, ABuf, w1t, beta);
  k_gemm1<<<8192, 256, 0, stream>>>(y0, y1, y2, y3, svec, TbufA, w1t, beta, tbuf, grnp);
  k_grn1<<<64, 256, 0, stream>>>(grnp, gpart);
  k_grn2<<<1, 1024, 0, stream>>>(gpart, grn_g, aBuf);
  k_w2prep<<<2, 512, 0, stream>>>(w2, aBuf, grn_b, w2t, cvec);
  k_gemm2<<<dim3(1024,2), 256, 0, stream>>>(tbuf, w2t, cvec, u_buf, upart);
  k_pbn<<<128, 256, 0, stream>>>(upart, pbn_w, pbn_b, ls_g, PQ);
  k_final<<<32768, 256, 0, stream>>>(u_buf, x, PQ, outp);
}

// Round 20
// 828.066 us; speedup vs baseline: 1.1719x; 1.1719x over previous
//
#include <hip/hip_runtime.h>
#include <stdint.h>

typedef unsigned short ush;
typedef unsigned int u32;
typedef __attribute__((ext_vector_type(8))) short short8;
typedef __attribute__((ext_vector_type(4))) float f32x4;
typedef __attribute__((ext_vector_type(2))) float f32x2;

#define DEVI static __device__ __forceinline__

constexpr int CC = 128, CH = 128;
constexpr int CS = 131072;           // H*W*Z per (n,c)
constexpr float BNEPS = 1e-5f;

DEVI ush f2bf(float f) {
  u32 u = __float_as_uint(f);
  u += 0x7FFF + ((u >> 16) & 1);     // RNE
  return (ush)(u >> 16);
}
DEVI float bf2f(ush h) { return __uint_as_float(((u32)h) << 16); }
DEVI float lo16(u32 u) { return __uint_as_float(u << 16); }
DEVI float hi16(u32 u) { return __uint_as_float(u & 0xFFFF0000u); }

DEVI float gelu_tanh(float v) {
  float y = 0.79788456f * (v + 0.044715f * v * v * v);
  float e = __expf(2.0f * y);
  return v * (1.0f - 1.0f / (e + 1.0f));
}

DEVI float wave_sum(float v) {
  v += __shfl_xor(v, 1);  v += __shfl_xor(v, 2);  v += __shfl_xor(v, 4);
  v += __shfl_xor(v, 8);  v += __shfl_xor(v, 16); v += __shfl_xor(v, 32);
  return v;
}

// packed acc update for z-split (v_pk_fma_f32 via fp-contract)
#define ACCZ2(A, P, K0, K1, K2, XV2, WP2) do {                                \
    if ((P) <= 3)             A[(P)][WP2]   += (K0) * (XV2);                  \
    if ((P) >= 1 && (P) <= 4) A[(P)-1][WP2] += (K1) * (XV2);                  \
    if ((P) >= 2)             A[(P)-2][WP2] += (K2) * (XV2);                  \
  } while (0)

template<int ZZ>
DEVI void conv_planes_bf(const ush* __restrict__ smb, int hh, int wt,
                         const float* __restrict__ lkc, const float* __restrict__ w5c,
                         const float* __restrict__ w3a, const float* __restrict__ w3b,
                         f32x2 (&a0)[4][2], f32x2 (&a1)[4][2],
                         f32x2 (&a2)[4][2], f32x2 (&a3)[4][2])
{
  constexpr int PLO = ZZ ? 0 : 1;
  constexpr int PHI = ZZ ? 5 : 6;
  #pragma unroll 1
  for (int dh = 0; dh < 7; ++dh) {
    const ush* smr = smb + (size_t)(hh + dh)*1088 + 4*wt;
    const bool b1on = (dh >= 1 && dh <= 5);
    const bool b2on = (dh & 1) != 0;
    const bool b3on = (dh == 0 || dh == 3 || dh == 6);
    #pragma unroll
    for (int p = PLO; p < PHI; ++p) {
      const int g = ZZ*4 + p - 1;
      const ush* q = smr + g*136;
      uint2 d0 = *(const uint2*)(q);
      uint2 d1 = *(const uint2*)(q + 4);
      uint2 d2 = *(const uint2*)(q + 8);
      float v[12] = {lo16(d0.x), hi16(d0.x), lo16(d0.y), hi16(d0.y),
                     lo16(d1.x), hi16(d1.x), lo16(d1.y), hi16(d1.y),
                     lo16(d2.x), hi16(d2.x), lo16(d2.y), hi16(d2.y)};
      #pragma unroll
      for (int dwi = 0; dwi < 7; ++dwi) {
        const float* cp = lkc + (dh*7 + dwi)*3;
        float k0 = cp[0], k1 = cp[1], k2 = cp[2];
        #pragma unroll
        for (int wp2 = 0; wp2 < 2; ++wp2) {
          f32x2 xv; xv.x = v[1 + 2*wp2 + dwi]; xv.y = v[2 + 2*wp2 + dwi];
          ACCZ2(a0, p, k0, k1, k2, xv, wp2);
        }
      }
      if (b1on) {
        #pragma unroll
        for (int dwi = 1; dwi <= 5; ++dwi) {
          const float* cp = w5c + ((dh-1)*5 + (dwi-1))*3;
          float k0 = cp[0], k1 = cp[1], k2 = cp[2];
          #pragma unroll
          for (int wp2 = 0; wp2 < 2; ++wp2) {
            f32x2 xv; xv.x = v[1 + 2*wp2 + dwi]; xv.y = v[2 + 2*wp2 + dwi];
            ACCZ2(a1, p, k0, k1, k2, xv, wp2);
          }
        }
      }
      if (b2on) {
        #pragma unroll
        for (int k = 0; k < 3; ++k) {
          const int dwi = 1 + 2*k;
          const float* cp = w3a + (((dh-1)>>1)*3 + k)*3;
          float k0 = cp[0], k1 = cp[1], k2 = cp[2];
          #pragma unroll
          for (int wp2 = 0; wp2 < 2; ++wp2) {
            f32x2 xv; xv.x = v[1 + 2*wp2 + dwi]; xv.y = v[2 + 2*wp2 + dwi];
            ACCZ2(a2, p, k0, k1, k2, xv, wp2);
          }
        }
      }
      if (b3on) {
        #pragma unroll
        for (int k = 0; k < 3; ++k) {
          const int dwi = 3*k;
          const float* cp = w3b + ((dh/3)*3 + k)*3;
          float k0 = cp[0], k1 = cp[1], k2 = cp[2];
          #pragma unroll
          for (int wp2 = 0; wp2 < 2; ++wp2) {
            f32x2 xv; xv.x = v[1 + 2*wp2 + dwi]; xv.y = v[2 + 2*wp2 + dwi];
            ACCZ2(a3, p, k0, k1, k2, xv, wp2);
          }
        }
      }
    }
  }
}

DEVI void acc_stats(const f32x2 (&a)[4][2], float& s, float& q) {
  #pragma unroll
  for (int z = 0; z < 4; ++z)
    #pragma unroll
    for (int wp2 = 0; wp2 < 2; ++wp2) {
      float e0 = a[z][wp2].x, e1 = a[z][wp2].y;
      s += e0; q = fmaf(e0, e0, q);
      s += e1; q = fmaf(e1, e1, q);
    }
}

DEVI void cross_stats(const f32x2 (&u)[4][2], const f32x2 (&w)[4][2], float& c) {
  #pragma unroll
  for (int z = 0; z < 4; ++z)
    #pragma unroll
    for (int wp2 = 0; wp2 < 2; ++wp2) {
      c = fmaf(u[z][wp2].x, w[z][wp2].x, c);
      c = fmaf(u[z][wp2].y, w[z][wp2].y, c);
    }
}

DEVI uint2 packz(const f32x2 (&a)[4][2], int wp) {
  const int h = wp >> 1, l = wp & 1;
  ush o0 = f2bf(a[0][h][l]), o1 = f2bf(a[1][h][l]);
  ush o2 = f2bf(a[2][h][l]), o3 = f2bf(a[3][h][l]);
  return make_uint2((u32)o0 | ((u32)o1 << 16), (u32)o2 | ((u32)o3 << 16));
}

// ---------------------------------------------------------------------------
// K1: 4-branch depthwise conv (once) -> bf16 branch outputs + 14 moments
// ---------------------------------------------------------------------------
__global__ __launch_bounds__(512) void k_conv4(
    const float* __restrict__ x, const float* __restrict__ lk_w,
    const float* __restrict__ dw5_w, const float* __restrict__ dw3a_w,
    const float* __restrict__ dw3b_w,
    ush* __restrict__ y0, ush* __restrict__ y1, ush* __restrict__ y2,
    ush* __restrict__ y3, float* __restrict__ part1)
{
  __shared__ __align__(16) ush smb[14*8*136];   // 30464B bf16 x tile
  __shared__ float red[8][14];
  const int hb = blockIdx.x, c = blockIdx.y, n = blockIdx.z, tid = threadIdx.x;
  const float* xc = x + ((size_t)(n*CC + c))*CS;
  #pragma unroll
  for (int i = 0; i < 7; ++i) {
    int idx = i*512 + tid;
    int row = idx >> 8, r4 = idx & 255;
    int w = r4 >> 1, zh = r4 & 1;
    int hin = hb*8 - 3 + row;
    float4 val = make_float4(0.f,0.f,0.f,0.f);
    if (hin >= 0 && hin < CH) val = *(const float4*)(xc + (size_t)hin*1024 + w*8 + zh*4);
    ush* base = smb + (row*8 + zh*4)*136 + 4 + w;
    base[0]   = f2bf(val.x);
    base[136] = f2bf(val.y);
    base[272] = f2bf(val.z);
    base[408] = f2bf(val.w);
  }
  for (int idx = tid; idx < 896; idx += 512) {   // zero w-halo: pw {0..3, 132..135}
    int row = idx >> 6, rem = idx & 63;
    int z = rem >> 3, col = rem & 7;
    int pw = (col < 4) ? col : (128 + col);
    smb[(row*8 + z)*136 + pw] = 0;
  }
  __syncthreads();

  const int wt = tid & 31, hh = (tid >> 5) & 7, zz = tid >> 8;
  f32x2 a0[4][2] = {}, a1[4][2] = {}, a2[4][2] = {}, a3[4][2] = {};
  if (zz == 0)
    conv_planes_bf<0>(smb, hh, wt, lk_w + c*147, dw5_w + c*75, dw3a_w + c*27, dw3b_w + c*27,
                      a0, a1, a2, a3);
  else
    conv_planes_bf<1>(smb, hh, wt, lk_w + c*147, dw5_w + c*75, dw3a_w + c*27, dw3b_w + c*27,
                      a0, a1, a2, a3);

  float s0=0,q0=0,s1=0,q1=0,s2=0,q2=0,s3=0,q3=0;
  acc_stats(a0, s0, q0); acc_stats(a1, s1, q1);
  acc_stats(a2, s2, q2); acc_stats(a3, s3, q3);
  float c01=0,c02=0,c03=0,c12=0,c13=0,c23=0;
  cross_stats(a0, a1, c01); cross_stats(a0, a2, c02); cross_stats(a0, a3, c03);
  cross_stats(a1, a2, c12); cross_stats(a1, a3, c13); cross_stats(a2, a3, c23);

  // ---- coalesced store via LDS exchange: 1 branch (16KB) per round ----
  char* exch = (char*)smb;           // smb dead; 16KB used
  const int hbase = hb*8;
  const size_t nbase = ((size_t)(n*CC + c))*CS;
  const int row_r = tid >> 6, j_r = tid & 63;
  const int wt_s = j_r >> 1, p0 = (j_r & 1)*2;
  const int sxor = (wt_s & 7) << 3;
  #pragma unroll
  for (int rnd = 0; rnd < 4; ++rnd) {
    const f32x2 (&aa)[4][2] = (rnd == 0) ? a0 : (rnd == 1) ? a1 : (rnd == 2) ? a2 : a3;
    ush* yb = (rnd == 0) ? y0 : (rnd == 1) ? y1 : (rnd == 2) ? y2 : y3;
    __syncthreads();                 // previous round's reads (or conv reads) done
    {
      const int wbyte = hh*2048 + wt*64;
      #pragma unroll
      for (int wp = 0; wp < 4; ++wp) {
        int swz = (wp*16 + zz*8) ^ ((wt & 7) << 3);
        *(uint2*)(exch + wbyte + swz) = packz(aa, wp);
      }
    }
    __syncthreads();
    {
      const char* src = exch + row_r*2048 + wt_s*64;
      uint2 e0 = *(const uint2*)(src + ((p0*16 + 0)  ^ sxor));
      uint2 e1 = *(const uint2*)(src + ((p0*16 + 8)  ^ sxor));
      uint2 e2 = *(const uint2*)(src + ((p0*16 + 16) ^ sxor));
      uint2 e3 = *(const uint2*)(src + ((p0*16 + 24) ^ sxor));
      ush* dst = yb + nbase + (size_t)(hbase + row_r)*1024 + j_r*16;
      *(uint4*)(dst)     = make_uint4(e0.x, e0.y, e1.x, e1.y);
      *(uint4*)(dst + 8) = make_uint4(e2.x, e2.y, e3.x, e3.y);
    }
  }

  float vals[14] = {s0,s1,s2,s3,q0,q1,q2,q3,c01,c02,c03,c12,c13,c23};
  #pragma unroll
  for (int jj = 0; jj < 14; ++jj) vals[jj] = wave_sum(vals[jj]);
  const int wid = tid >> 6, lane = tid & 63;
  if (lane == 0) {
    #pragma unroll
    for (int jj = 0; jj < 14; ++jj) red[wid][jj] = vals[jj];
  }
  __syncthreads();
  if (tid < 14) {
    float s = 0.f;
    #pragma unroll
    for (int w2 = 0; w2 < 8; ++w2) s += red[w2][tid];
    part1[(((size_t)n*CC + c)*16 + hb)*16 + tid] = s;
  }
}

// ---------------------------------------------------------------------------
// K2: merged stats: per-branch BN -> svec/T; analytic combined BN; SE -> ABuf
// ---------------------------------------------------------------------------
__global__ __launch_bounds__(512) void k_stats(
    const float* __restrict__ part1,
    const float* bn0_w, const float* bn0_b, const float* dbn1_w, const float* dbn1_b,
    const float* dbn2_w, const float* dbn2_b, const float* dbn3_w, const float* dbn3_b,
    const float* nrm_w, const float* nrm_b,
    const float* se_dw, const float* se_db, const float* se_uw, const float* se_ub,
    float* __restrict__ svec, float* __restrict__ Tbuf, float* __restrict__ ABuf)
{
  __shared__ float sA[4][128], tA[4][128], QA[4][128], S0A[4][128], SfA[4][128];
  __shared__ float pmA[2][128], hA[2][32], alA[128], beA[128];
  const int tid = threadIdx.x;
  {
    int c = tid >> 2, b = tid & 3;
    float s_f = 0.f, s_0 = 0.f, q = 0.f;
    for (int n = 0; n < 2; n++)
      for (int hb = 0; hb < 16; hb++) {
        const float* p = part1 + (((size_t)n*CC + c)*16 + hb)*16;
        float v = p[b];
        s_f += v; if (n == 0) s_0 += v;
        q += p[4 + b];
      }
    float mean = s_f * (1.f/262144.f);
    float var  = q * (1.f/262144.f) - mean*mean;
    float g, bb;
    if (b == 0)      { g = bn0_w[c];  bb = bn0_b[c];  }
    else if (b == 1) { g = dbn1_w[c]; bb = dbn1_b[c]; }
    else if (b == 2) { g = dbn2_w[c]; bb = dbn2_b[c]; }
    else             { g = dbn3_w[c]; bb = dbn3_b[c]; }
    float sc = g * rsqrtf(var + BNEPS);
    svec[c*4 + b] = sc;
    sA[b][c] = sc;
    tA[b][c] = bb - mean * sc;
    QA[b][c] = q; S0A[b][c] = s_0; SfA[b][c] = s_f;
  }
  __syncthreads();
  if (tid < 128) {
    int c = tid;
    float cr[6] = {0,0,0,0,0,0};
    for (int n = 0; n < 2; n++)
      for (int hb = 0; hb < 16; hb++) {
        const float* p = part1 + (((size_t)n*CC + c)*16 + hb)*16 + 8;
        #pragma unroll
        for (int k = 0; k < 6; k++) cr[k] += p[k];
      }
    float s0 = sA[0][c], s1 = sA[1][c], s2 = sA[2][c], s3 = sA[3][c];
    float T = tA[0][c] + tA[1][c] + tA[2][c] + tA[3][c];
    Tbuf[c] = T;
    float wf = s0*SfA[0][c] + s1*SfA[1][c] + s2*SfA[2][c] + s3*SfA[3][c];
    float w0 = s0*S0A[0][c] + s1*S0A[1][c] + s2*S0A[2][c] + s3*S0A[3][c];
    float sum_full = wf + 262144.f*T;
    float sumsq = s0*s0*QA[0][c] + s1*s1*QA[1][c] + s2*s2*QA[2][c] + s3*s3*QA[3][c]
                + 2.f*(s0*s1*cr[0] + s0*s2*cr[1] + s0*s3*cr[2]
                     + s1*s2*cr[3] + s1*s3*cr[4] + s2*s3*cr[5])
                + 2.f*T*wf + 262144.f*T*T;
    float m   = sum_full * (1.f/262144.f);
    float var = sumsq * (1.f/262144.f) - m*m;
    float inv = rsqrtf(var + BNEPS);
    float al = nrm_w[c]*inv;
    float be = nrm_b[c] - m*al;
    alA[c] = al; beA[c] = be;
    float sum_n0 = w0 + 131072.f*T;
    float sum_n1 = (wf - w0) + 131072.f*T;
    pmA[0][c] = (sum_n0*(1.f/131072.f) - m)*al + be;
    pmA[1][c] = (sum_n1*(1.f/131072.f) - m)*al + be;
  }
  __syncthreads();
  if (tid < 64) {
    int n = tid >> 5, i = tid & 31;
    float h = se_db[i];
    for (int c2 = 0; c2 < 128; c2++) h += pmA[n][c2]*se_dw[i*128 + c2];
    hA[n][i] = fmaxf(h, 0.f);
  }
  __syncthreads();
  if (tid < 256) {
    int n = tid >> 7, c = tid & 127;
    float sse = se_ub[c];
    #pragma unroll
    for (int i = 0; i < 32; i++) sse += hA[n][i]*se_uw[c*32 + i];
    ABuf[(n*128 + c)*2 + 0] = alA[c]*sse;
    ABuf[(n*128 + c)*2 + 1] = beA[c]*sse;
  }
}

// ---------------------------------------------------------------------------
// K5: fold A into w1 (bf16, [n][f][c]) and B into beta[n][f]
// ---------------------------------------------------------------------------
__global__ __launch_bounds__(512) void k_w1prep(
    const float* __restrict__ w1, const float* __restrict__ b1,
    const float* __restrict__ ABuf, ush* __restrict__ w1t, float* __restrict__ beta)
{
  const int n = blockIdx.x, tid = threadIdx.x;
  __shared__ float Asc[128], Bsc[128];
  if (tid < 128) { Asc[tid] = ABuf[(n*128 + tid)*2]; Bsc[tid] = ABuf[(n*128 + tid)*2 + 1]; }
  __syncthreads();
  for (int i = tid; i < 512*128; i += 512) {     // write-contiguous
    int f = i >> 7, cc = i & 127;
    w1t[((size_t)n*512 + f)*128 + cc] = f2bf(w1[cc*512 + f] * Asc[cc]);
  }
  {
    int f = tid;
    float s = b1[f];
    for (int cc = 0; cc < 128; cc++) s += Bsc[cc]*w1[cc*512 + f];
    beta[n*512 + f] = s;
  }
}

// ---------------------------------------------------------------------------
// K7: GEMM1, one block per (mt,n): combine A ONCE (granule-swizzle transpose
// via Bl scratch), keep in Al, loop ft=0..3 {stage B, MFMA, gelu, store}.
// ---------------------------------------------------------------------------
__global__ __launch_bounds__(256) void k_gemm1(
    const ush* __restrict__ y0, const ush* __restrict__ y1,
    const ush* __restrict__ y2, const ush* __restrict__ y3,
    const float* __restrict__ svec, const float* __restrict__ Tb,
    const ush* __restrict__ w1t, const float* __restrict__ beta,
    ush* __restrict__ tbuf, float* __restrict__ grnp)
{
  __shared__ __align__(16) ush Al[16384];
  __shared__ __align__(16) ush Bl[16384];
  __shared__ float grnl[256];
  const int l = blockIdx.x, tid = threadIdx.x;
  const int mt = l >> 1, n = l & 1;

  // step 1: combine branches into Bl (granule-swizzled transpose scratch)
  #pragma unroll
  for (int i = 0; i < 8; i++) {
    int g = i*256 + tid;
    int cc = g >> 4, s8 = g & 15;
    size_t off = ((size_t)(n*CC + cc))*CS + (size_t)mt*128 + s8*8;
    uint4 v0 = *(const uint4*)(y0 + off);
    uint4 v1 = *(const uint4*)(y1 + off);
    uint4 v2 = *(const uint4*)(y2 + off);
    uint4 v3 = *(const uint4*)(y3 + off);
    float4 sv = *(const float4*)(svec + cc*4);
    float Tc = Tb[cc];
    union { uint4 q; ush e[8]; } u0, u1, u2, u3, uo;
    u0.q = v0; u1.q = v1; u2.q = v2; u3.q = v3;
    #pragma unroll
    for (int j = 0; j < 8; j++) {
      float y = sv.x*bf2f(u0.e[j]) + sv.y*bf2f(u1.e[j])
              + sv.z*bf2f(u2.e[j]) + sv.w*bf2f(u3.e[j]) + Tc;
      uo.e[j] = f2bf(y);
    }
    #pragma unroll
    for (int j = 0; j < 8; j++) {
      int s_l = s8*8 + j;
      int gran = s_l*16 + ((cc >> 3) ^ (s8 & 7));
      Bl[gran*8 + (cc & 7)] = uo.e[j];
    }
  }
  __syncthreads();
  // step 2: read NSC 16B chunks out of the granule layout
  uint4 areg[8];
  #pragma unroll
  for (int i = 0; i < 8; i++) {
    int idx = i*256 + tid;
    int s_l = idx >> 4, gc = idx & 15;
    int gran = s_l*16 + (gc ^ ((s_l >> 3) & 7));
    areg[i] = *(const uint4*)&Bl[gran*8];
  }
  // step 3: place A MFMA-swizzled in Al (Bl reads done after barrier below)
  __syncthreads();
  #pragma unroll
  for (int i = 0; i < 8; i++) {
    int idx = i*256 + tid;
    int rr = idx >> 4, cg = idx & 15;
    *(uint4*)&Al[rr*128 + ((cg ^ (rr & 7))*8)] = areg[i];
  }

  const int wid = tid >> 6, lane = tid & 63;
  const int wm = wid >> 1, wn = wid & 1;
  const int lr = lane & 15, lk = lane >> 4;

  #pragma unroll 1
  for (int ft = 0; ft < 4; ++ft) {
    __syncthreads();          // Al visible (ft=0); prior Bl scatter-reads done
    const ush* Bb = w1t + ((size_t)n*512 + (size_t)ft*128) * 128;
    #pragma unroll
    for (int i = 0; i < 8; i++) {
      int idx = i*256 + tid;
      int rr = idx >> 4, cg = idx & 15;
      *(uint4*)&Bl[rr*128 + ((cg ^ (rr & 7))*8)] = *(const uint4*)(Bb + (size_t)idx*8);
    }
    __syncthreads();

    f32x4 acc[4][4] = {};
    #pragma unroll
    for (int kk = 0; kk < 4; kk++) {
      short8 af[4], bfr[4];
      #pragma unroll
      for (int mf = 0; mf < 4; mf++) {
        int row = wm*64 + mf*16 + lr;
        int cg = (kk*4 + lk) ^ (row & 7);
        af[mf] = *(const short8*)&Al[row*128 + cg*8];
      }
      #pragma unroll
      for (int nf = 0; nf < 4; nf++) {
        int row = wn*64 + nf*16 + lr;
        int cg = (kk*4 + lk) ^ (row & 7);
        bfr[nf] = *(const short8*)&Bl[row*128 + cg*8];
      }
      #pragma unroll
      for (int mf = 0; mf < 4; mf++)
        #pragma unroll
        for (int nf = 0; nf < 4; nf++)
          acc[mf][nf] = __builtin_amdgcn_mfma_f32_16x16x32_bf16(af[mf], bfr[nf], acc[mf][nf], 0, 0, 0);
    }

    float bt[4];
    #pragma unroll
    for (int nf = 0; nf < 4; nf++) bt[nf] = beta[n*512 + ft*128 + wn*64 + nf*16 + lr];
    float sq[4] = {0.f,0.f,0.f,0.f};
    #pragma unroll
    for (int mf = 0; mf < 4; mf++)
      #pragma unroll
      for (int nf = 0; nf < 4; nf++)
        #pragma unroll
        for (int rg = 0; rg < 4; rg++) {
          float g = gelu_tanh(acc[mf][nf][rg] + bt[nf]);
          sq[nf] += g*g;
          acc[mf][nf][rg] = g;
        }
    __syncthreads();          // MFMA reads of Bl done
    #pragma unroll
    for (int nf = 0; nf < 4; nf++) {
      float v = sq[nf];
      v += __shfl_xor(v, 16); v += __shfl_xor(v, 32);
      if (lane < 16) grnl[(wn*64 + nf*16 + lane)*2 + wm] = v;
    }
    #pragma unroll
    for (int mf = 0; mf < 4; mf++)
      #pragma unroll
      for (int nf = 0; nf < 4; nf++)
        #pragma unroll
        for (int rg = 0; rg < 4; rg++) {
          int ml = wm*64 + mf*16 + lk*4 + rg;
          int fl = wn*64 + nf*16 + lr;
          Bl[ml*128 + (fl ^ (((ml >> 2) & 3) << 4))] = f2bf(acc[mf][nf][rg]);
        }
    __syncthreads();
    #pragma unroll
    for (int i = 0; i < 8; i++) {
      int idx = i*256 + tid;
      int m = idx >> 4, gc = idx & 15;
      uint4 v = *(const uint4*)&Bl[m*128 + ((gc ^ (((m >> 2) & 3) << 1))*8)];
      *(uint4*)(tbuf + ((size_t)n*CS + (size_t)mt*128 + m)*512 + ft*128 + gc*8) = v;
    }
    if (tid < 128) grnp[(size_t)mt*1024 + n*512 + ft*128 + tid] = grnl[tid*2] + grnl[tid*2+1];
  }
}

// K8a: GRN partial reduce over mt (64 blocks)
__global__ __launch_bounds__(256) void k_grn1(
    const float* __restrict__ grnp, float* __restrict__ gpart)
{
  const int j = blockIdx.x, tid = threadIdx.x;
  float acc[4] = {0.f, 0.f, 0.f, 0.f};
  for (int i = 0; i < 16; ++i) {
    const float* p = grnp + (size_t)(j*16 + i)*1024;
    #pragma unroll
    for (int ch = 0; ch < 4; ++ch) acc[ch] += p[ch*256 + tid];
  }
  #pragma unroll
  for (int ch = 0; ch < 4; ++ch) gpart[(size_t)j*1024 + ch*256 + tid] = acc[ch];
}

// K8b: GRN final: Gx -> Nx -> a[n][f] = grn_g*Nx + 1
__global__ __launch_bounds__(1024) void k_grn2(
    const float* __restrict__ gpart, const float* __restrict__ grn_g, float* __restrict__ aBuf)
{
  __shared__ float wsum[16], gm[2];
  const int tid = threadIdx.x;
  float s = 0.f;
  for (int j = 0; j < 64; ++j) s += gpart[(size_t)j*1024 + tid];
  float Gx = sqrtf(s);
  float v = wave_sum(Gx);
  if ((tid & 63) == 0) wsum[tid >> 6] = v;
  __syncthreads();
  if (tid < 2) {
    float m = 0.f;
    #pragma unroll
    for (int w2 = 0; w2 < 8; w2++) m += wsum[tid*8 + w2];
    gm[tid] = m * (1.f/512.f) + 1e-6f;
  }
  __syncthreads();
  int n = tid >> 9, f = tid & 511;
  aBuf[tid] = grn_g[f] * (Gx / gm[n]) + 1.f;
}

// K9: w2t[n][co][f] = w2[f][co]*a[n][f]  (bf16)  + cvec (n==0 block)
__global__ __launch_bounds__(512) void k_w2prep(
    const float* __restrict__ w2, const float* __restrict__ aBuf,
    const float* __restrict__ grn_b, ush* __restrict__ w2t, float* __restrict__ cvec)
{
  const int n = blockIdx.x, tid = threadIdx.x;
  for (int i = tid; i < 128*512; i += 512) {     // write-contiguous
    int co = i >> 9, f = i & 511;
    w2t[((size_t)n*128 + co)*512 + f] = f2bf(w2[(size_t)f*128 + co] * aBuf[n*512 + f]);
  }
  if (n == 0) {
    __shared__ float cs[4][128];
    int co = tid & 127, qh = tid >> 7;
    float s = 0.f;
    for (int f = qh*128; f < qh*128 + 128; ++f) s += grn_b[f]*w2[(size_t)f*128 + co];
    cs[qh][co] = s;
    __syncthreads();
    if (tid < 128) cvec[tid] = cs[0][tid] + cs[1][tid] + cs[2][tid] + cs[3][tid];
  }
}

// ---------------------------------------------------------------------------
// K11: GEMM2  u (NCS layout) = t @ w2t_n^T + cvec, bf16 out + post-BN partials
// ---------------------------------------------------------------------------
__global__ __launch_bounds__(256) void k_gemm2(
    const ush* __restrict__ tbuf, const ush* __restrict__ w2t,
    const float* __restrict__ cvec, ush* __restrict__ u, float* __restrict__ upart)
{
  __shared__ __align__(16) ush Al[16384];
  __shared__ __align__(16) ush Bl[16384];
  const int mt = blockIdx.x, n = blockIdx.y, tid = threadIdx.x;
  const int wid = tid >> 6, lane = tid & 63;
  const int wm = wid >> 1, wn = wid & 1;
  const int lr = lane & 15, lk = lane >> 4;
  f32x4 acc[4][4] = {};
  #pragma unroll 1
  for (int kb = 0; kb < 4; kb++) {
    if (kb) __syncthreads();
    #pragma unroll
    for (int i = 0; i < 8; i++) {
      int g = i*256 + tid;
      int rr = g >> 4, cg = g & 15;
      *(uint4*)&Al[rr*128 + ((cg ^ (rr & 7))*8)] =
        *(const uint4*)(tbuf + ((size_t)n*CS + (size_t)mt*128 + rr)*512 + kb*128 + cg*8);
      *(uint4*)&Bl[rr*128 + ((cg ^ (rr & 7))*8)] =
        *(const uint4*)(w2t + ((size_t)n*128 + rr)*512 + kb*128 + cg*8);
    }
    __syncthreads();
    #pragma unroll
    for (int kk = 0; kk < 4; kk++) {
      short8 af[4], bfr[4];
      #pragma unroll
      for (int mf = 0; mf < 4; mf++) {
        int row = wm*64 + mf*16 + lr;
        int cg = (kk*4 + lk) ^ (row & 7);
        af[mf] = *(const short8*)&Al[row*128 + cg*8];
      }
      #pragma unroll
      for (int nf = 0; nf < 4; nf++) {
        int row = wn*64 + nf*16 + lr;
        int cg = (kk*4 + lk) ^ (row & 7);
        bfr[nf] = *(const short8*)&Bl[row*128 + cg*8];
      }
      #pragma unroll
      for (int mf = 0; mf < 4; mf++)
        #pragma unroll
        for (int nf = 0; nf < 4; nf++)
          acc[mf][nf] = __builtin_amdgcn_mfma_f32_16x16x32_bf16(af[mf], bfr[nf], acc[mf][nf], 0, 0, 0);
    }
  }
  float cv[4];
  #pragma unroll
  for (int nf = 0; nf < 4; nf++) cv[nf] = cvec[wn*64 + nf*16 + lr];
  float su[4] = {0,0,0,0}, sq[4] = {0,0,0,0};
  #pragma unroll
  for (int mf = 0; mf < 4; mf++)
    #pragma unroll
    for (int nf = 0; nf < 4; nf++)
      #pragma unroll
      for (int rg = 0; rg < 4; rg++) {
        float v = acc[mf][nf][rg] + cv[nf];
        su[nf] += v; sq[nf] += v*v;
        acc[mf][nf][rg] = v;
      }
  __syncthreads();
  float* stl = (float*)Al;
  #pragma unroll
  for (int nf = 0; nf < 4; nf++) {
    float a = su[nf]; a += __shfl_xor(a, 16); a += __shfl_xor(a, 32);
    float b = sq[nf]; b += __shfl_xor(b, 16); b += __shfl_xor(b, 32);
    if (lane < 16) {
      stl[((wn*64 + nf*16 + lane)*2 + wm)*2 + 0] = a;
      stl[((wn*64 + nf*16 + lane)*2 + wm)*2 + 1] = b;
    }
  }
  // transposed scatter: Bl row = c index (fl), col = s index (ml)
  #pragma unroll
  for (int mf = 0; mf < 4; mf++)
    #pragma unroll
    for (int nf = 0; nf < 4; nf++)
      #pragma unroll
      for (int rg = 0; rg < 4; rg++) {
        int ml = wm*64 + mf*16 + lk*4 + rg;
        int fl = wn*64 + nf*16 + lr;
        Bl[fl*128 + (ml ^ (((fl >> 2) & 3) << 4))] = f2bf(acc[mf][nf][rg]);
      }
  __syncthreads();
  #pragma unroll
  for (int i = 0; i < 8; i++) {
    int idx = i*256 + tid;
    int cr = idx >> 4, gm = idx & 15;
    uint4 v = *(const uint4*)&Bl[cr*128 + ((gm ^ (((cr >> 2) & 3) << 1))*8)];
    *(uint4*)(u + ((size_t)(n*CC + cr))*CS + (size_t)mt*128 + gm*8) = v;
  }
  if (tid < 128) {
    float s = stl[(tid*2 + 0)*2 + 0] + stl[(tid*2 + 1)*2 + 0];
    float q = stl[(tid*2 + 0)*2 + 1] + stl[(tid*2 + 1)*2 + 1];
    upart[((size_t)(n*1024 + mt)*128 + tid)*2 + 0] = s;
    upart[((size_t)(n*1024 + mt)*128 + tid)*2 + 1] = q;
  }
}

// K12: post-BN stats -> P,Q per channel
__global__ __launch_bounds__(256) void k_pbn(
    const float* __restrict__ upart, const float* pbn_w, const float* pbn_b,
    const float* ls_g, float* __restrict__ PQ)
{
  __shared__ float rs[4], rq[4];
  const int c = blockIdx.x, tid = threadIdx.x;
  float s = 0.f, q = 0.f;
  for (int mtg = tid; mtg < 2048; mtg += 256) {
    s += upart[((size_t)mtg*128 + c)*2 + 0];
    q += upart[((size_t)mtg*128 + c)*2 + 1];
  }
  s = wave_sum(s); q = wave_sum(q);
  if ((tid & 63) == 0) { rs[tid >> 6] = s; rq[tid >> 6] = q; }
  __syncthreads();
  if (tid == 0) {
    float S = rs[0]+rs[1]+rs[2]+rs[3];
    float Qq = rq[0]+rq[1]+rq[2]+rq[3];
    float m = S*(1.f/262144.f);
    float var = Qq*(1.f/262144.f) - m*m;
    float inv = rsqrtf(var + BNEPS);
    PQ[c*2 + 0] = ls_g[c]*pbn_w[c]*inv;
    PQ[c*2 + 1] = ls_g[c]*(pbn_b[c] - m*inv*pbn_w[c]);
  }
}

// K13: out[n,c,s] = x + u_ncs*P[c] + Q[c]  — the ONLY writer of d_out
__global__ __launch_bounds__(256) void k_final(
    const ush* __restrict__ u, const float* __restrict__ x,
    const float* __restrict__ PQ, float* __restrict__ out)
{
  size_t e = ((size_t)blockIdx.x*256 + threadIdx.x)*4;
  int c = (int)((e >> 17) & 127);
  float P = PQ[c*2], Q = PQ[c*2 + 1];
  uint2 uv = *(const uint2*)(u + e);
  float4 xv = *(const float4*)(x + e);
  float4 o;
  o.x = fmaf(bf2f((ush)(uv.x & 0xffff)), P, xv.x + Q);
  o.y = fmaf(bf2f((ush)(uv.x >> 16)),   P, xv.y + Q);
  o.z = fmaf(bf2f((ush)(uv.y & 0xffff)), P, xv.z + Q);
  o.w = fmaf(bf2f((ush)(uv.y >> 16)),   P, xv.w + Q);
  *(float4*)(out + e) = o;
}

// ---------------------------------------------------------------------------
extern "C" void kernel_launch(void* const* d_in, const int* in_sizes, int n_in,
                              void* d_out, int out_size, void* d_ws, size_t ws_size,
                              hipStream_t stream)
{
  (void)in_sizes; (void)n_in; (void)out_size; (void)ws_size;
  const float* x      = (const float*)d_in[0];
  const float* lk_w   = (const float*)d_in[1];
  const float* bn0_w  = (const float*)d_in[2];
  const float* bn0_b  = (const float*)d_in[3];
  const float* dw5_w  = (const float*)d_in[4];
  const float* dbn1_w = (const float*)d_in[5];
  const float* dbn1_b = (const float*)d_in[6];
  const float* dw3a_w = (const float*)d_in[7];
  const float* dbn2_w = (const float*)d_in[8];
  const float* dbn2_b = (const float*)d_in[9];
  const float* dw3b_w = (const float*)d_in[10];
  const float* dbn3_w = (const float*)d_in[11];
  const float* dbn3_b = (const float*)d_in[12];
  const float* nrm_w  = (const float*)d_in[13];
  const float* nrm_b  = (const float*)d_in[14];
  const float* se_dw  = (const float*)d_in[15];
  const float* se_db  = (const float*)d_in[16];
  const float* se_uw  = (const float*)d_in[17];
  const float* se_ub  = (const float*)d_in[18];
  const float* w1     = (const float*)d_in[19];
  const float* b1     = (const float*)d_in[20];
  const float* grn_g  = (const float*)d_in[21];
  const float* grn_b  = (const float*)d_in[22];
  const float* w2     = (const float*)d_in[23];
  const float* pbn_w  = (const float*)d_in[24];
  const float* pbn_b  = (const float*)d_in[25];
  const float* ls_g   = (const float*)d_in[26];

  char* w = (char*)d_ws;
  size_t cur = 0;
  auto take = [&](size_t b) { size_t r = cur; cur += (b + 255) & ~(size_t)255; return r; };
  ush*   tbuf  = (ush*)  (w + take((size_t)2*CS*512*2));   // 268.4MB; y0..y3 alias (exact fit)
  ush*   ycl_u = (ush*)  (w + take((size_t)2*CS*128*2));   // 67.1MB; u
  float* partU = (float*)(w + take((size_t)2*512*128*2*4));// part1 (16/slot)
  float* svec  = (float*)(w + take(128*4*4));
  float* TbufA = (float*)(w + take(128*4));
  float* ABuf  = (float*)(w + take(2*128*2*4));
  ush*   w1t   = (ush*)  (w + take(2*512*128*2));
  float* beta  = (float*)(w + take(2*512*4));
  float* grnpU = (float*)(w + take((size_t)1024*1024*4));  // grnp then upart
  float* gpart = (float*)(w + take((size_t)64*1024*4));
  float* aBuf  = (float*)(w + take(2*512*4));
  ush*   w2t   = (ush*)  (w + take(2*128*512*2));
  float* cvec  = (float*)(w + take(128*4));
  float* PQ    = (float*)(w + take(128*2*4));

  const size_t YSZ = (size_t)2*CC*CS;         // 33.5M ush per branch buffer
  ush*   y0    = tbuf;
  ush*   y1    = tbuf + YSZ;
  ush*   y2    = tbuf + 2*YSZ;
  ush*   y3    = tbuf + 3*YSZ;
  ush*   u_buf = ycl_u;
  float* part1 = partU;
  float* grnp  = grnpU;
  float* upart = grnpU;
  float* outp  = (float*)d_out;

  k_conv4<<<dim3(16,128,2), 512, 0, stream>>>(x, lk_w, dw5_w, dw3a_w, dw3b_w,
                                              y0, y1, y2, y3, part1);
  k_stats<<<1, 512, 0, stream>>>(part1, bn0_w, bn0_b, dbn1_w, dbn1_b,
                                 dbn2_w, dbn2_b, dbn3_w, dbn3_b,
                                 nrm_w, nrm_b, se_dw, se_db, se_uw, se_ub,
                                 svec, TbufA, ABuf);
  k_w1prep<<<2, 512, 0, stream>>>(w1, b1, ABuf, w1t, beta);
  k_gemm1<<<2048, 256, 0, stream>>>(y0, y1, y2, y3, svec, TbufA, w1t, beta, tbuf, grnp);
  k_grn1<<<64, 256, 0, stream>>>(grnp, gpart);
  k_grn2<<<1, 1024, 0, stream>>>(gpart, grn_g, aBuf);
  k_w2prep<<<2, 512, 0, stream>>>(w2, aBuf, grn_b, w2t, cvec);
  k_gemm2<<<dim3(1024,2), 256, 0, stream>>>(tbuf, w2t, cvec, u_buf, upart);
  k_pbn<<<128, 256, 0, stream>>>(upart, pbn_w, pbn_b, ls_g, PQ);
  k_final<<<32768, 256, 0, stream>>>(u_buf, x, PQ, outp);
}

// Round 21
// 709.626 us; speedup vs baseline: 1.3674x; 1.1669x over previous
//
#include <hip/hip_runtime.h>
#include <stdint.h>

typedef unsigned short ush;
typedef unsigned int u32;
typedef __attribute__((ext_vector_type(8))) short short8;
typedef __attribute__((ext_vector_type(4))) float f32x4;
typedef __attribute__((ext_vector_type(2))) float f32x2;

#define DEVI static __device__ __forceinline__

constexpr int CC = 128, CH = 128;
constexpr int CS = 131072;           // H*W*Z per (n,c)
constexpr float BNEPS = 1e-5f;

DEVI ush f2bf(float f) {
  u32 u = __float_as_uint(f);
  u += 0x7FFF + ((u >> 16) & 1);     // RNE
  return (ush)(u >> 16);
}
DEVI float bf2f(ush h) { return __uint_as_float(((u32)h) << 16); }
DEVI float lo16(u32 u) { return __uint_as_float(u << 16); }
DEVI float hi16(u32 u) { return __uint_as_float(u & 0xFFFF0000u); }

DEVI float gelu_tanh(float v) {
  float y = 0.79788456f * (v + 0.044715f * v * v * v);
  float e = __expf(2.0f * y);
  return v * (1.0f - 1.0f / (e + 1.0f));
}

DEVI float wave_sum(float v) {
  v += __shfl_xor(v, 1);  v += __shfl_xor(v, 2);  v += __shfl_xor(v, 4);
  v += __shfl_xor(v, 8);  v += __shfl_xor(v, 16); v += __shfl_xor(v, 32);
  return v;
}

// packed acc update for z-split (v_pk_fma_f32 via fp-contract)
#define ACCZ2(A, P, K0, K1, K2, XV2, WP2) do {                                \
    if ((P) <= 3)             A[(P)][WP2]   += (K0) * (XV2);                  \
    if ((P) >= 1 && (P) <= 4) A[(P)-1][WP2] += (K1) * (XV2);                  \
    if ((P) >= 2)             A[(P)-2][WP2] += (K2) * (XV2);                  \
  } while (0)

template<int ZZ>
DEVI void conv_planes_bf(const ush* __restrict__ smb, int hh, int wt,
                         const float* __restrict__ lkc, const float* __restrict__ w5c,
                         const float* __restrict__ w3a, const float* __restrict__ w3b,
                         f32x2 (&a0)[4][2], f32x2 (&a1)[4][2],
                         f32x2 (&a2)[4][2], f32x2 (&a3)[4][2])
{
  constexpr int PLO = ZZ ? 0 : 1;
  constexpr int PHI = ZZ ? 5 : 6;
  #pragma unroll 1
  for (int dh = 0; dh < 7; ++dh) {
    const ush* smr = smb + (size_t)(hh + dh)*1088 + 4*wt;
    const bool b1on = (dh >= 1 && dh <= 5);
    const bool b2on = (dh & 1) != 0;
    const bool b3on = (dh == 0 || dh == 3 || dh == 6);
    #pragma unroll
    for (int p = PLO; p < PHI; ++p) {
      const int g = ZZ*4 + p - 1;
      const ush* q = smr + g*136;
      uint2 d0 = *(const uint2*)(q);
      uint2 d1 = *(const uint2*)(q + 4);
      uint2 d2 = *(const uint2*)(q + 8);
      float v[12] = {lo16(d0.x), hi16(d0.x), lo16(d0.y), hi16(d0.y),
                     lo16(d1.x), hi16(d1.x), lo16(d1.y), hi16(d1.y),
                     lo16(d2.x), hi16(d2.x), lo16(d2.y), hi16(d2.y)};
      #pragma unroll
      for (int dwi = 0; dwi < 7; ++dwi) {
        const float* cp = lkc + (dh*7 + dwi)*3;
        float k0 = cp[0], k1 = cp[1], k2 = cp[2];
        #pragma unroll
        for (int wp2 = 0; wp2 < 2; ++wp2) {
          f32x2 xv; xv.x = v[1 + 2*wp2 + dwi]; xv.y = v[2 + 2*wp2 + dwi];
          ACCZ2(a0, p, k0, k1, k2, xv, wp2);
        }
      }
      if (b1on) {
        #pragma unroll
        for (int dwi = 1; dwi <= 5; ++dwi) {
          const float* cp = w5c + ((dh-1)*5 + (dwi-1))*3;
          float k0 = cp[0], k1 = cp[1], k2 = cp[2];
          #pragma unroll
          for (int wp2 = 0; wp2 < 2; ++wp2) {
            f32x2 xv; xv.x = v[1 + 2*wp2 + dwi]; xv.y = v[2 + 2*wp2 + dwi];
            ACCZ2(a1, p, k0, k1, k2, xv, wp2);
          }
        }
      }
      if (b2on) {
        #pragma unroll
        for (int k = 0; k < 3; ++k) {
          const int dwi = 1 + 2*k;
          const float* cp = w3a + (((dh-1)>>1)*3 + k)*3;
          float k0 = cp[0], k1 = cp[1], k2 = cp[2];
          #pragma unroll
          for (int wp2 = 0; wp2 < 2; ++wp2) {
            f32x2 xv; xv.x = v[1 + 2*wp2 + dwi]; xv.y = v[2 + 2*wp2 + dwi];
            ACCZ2(a2, p, k0, k1, k2, xv, wp2);
          }
        }
      }
      if (b3on) {
        #pragma unroll
        for (int k = 0; k < 3; ++k) {
          const int dwi = 3*k;
          const float* cp = w3b + ((dh/3)*3 + k)*3;
          float k0 = cp[0], k1 = cp[1], k2 = cp[2];
          #pragma unroll
          for (int wp2 = 0; wp2 < 2; ++wp2) {
            f32x2 xv; xv.x = v[1 + 2*wp2 + dwi]; xv.y = v[2 + 2*wp2 + dwi];
            ACCZ2(a3, p, k0, k1, k2, xv, wp2);
          }
        }
      }
    }
  }
}

DEVI void acc_stats(const f32x2 (&a)[4][2], float& s, float& q) {
  #pragma unroll
  for (int z = 0; z < 4; ++z)
    #pragma unroll
    for (int wp2 = 0; wp2 < 2; ++wp2) {
      float e0 = a[z][wp2].x, e1 = a[z][wp2].y;
      s += e0; q = fmaf(e0, e0, q);
      s += e1; q = fmaf(e1, e1, q);
    }
}

DEVI void cross_stats(const f32x2 (&u)[4][2], const f32x2 (&w)[4][2], float& c) {
  #pragma unroll
  for (int z = 0; z < 4; ++z)
    #pragma unroll
    for (int wp2 = 0; wp2 < 2; ++wp2) {
      c = fmaf(u[z][wp2].x, w[z][wp2].x, c);
      c = fmaf(u[z][wp2].y, w[z][wp2].y, c);
    }
}

DEVI uint2 packz(const f32x2 (&a)[4][2], int wp) {
  const int h = wp >> 1, l = wp & 1;
  ush o0 = f2bf(a[0][h][l]), o1 = f2bf(a[1][h][l]);
  ush o2 = f2bf(a[2][h][l]), o3 = f2bf(a[3][h][l]);
  return make_uint2((u32)o0 | ((u32)o1 << 16), (u32)o2 | ((u32)o3 << 16));
}

// ---------------------------------------------------------------------------
// K1: 4-branch depthwise conv (once) -> bf16 branch outputs + 14 moments.
// 256 thr / 4 output h-rows: tile 10x8x136 bf16 = 21.8KB -> ~6 blocks/CU
// (independent blocks hide LDS/VALU latency). Plain __launch_bounds__(256):
// NO waves-per-eu hint (R14/R15: hints capping VGPR below natural use cause
// catastrophic scratch spill).
// ---------------------------------------------------------------------------
__global__ __launch_bounds__(256) void k_conv4(
    const float* __restrict__ x, const float* __restrict__ lk_w,
    const float* __restrict__ dw5_w, const float* __restrict__ dw3a_w,
    const float* __restrict__ dw3b_w,
    ush* __restrict__ y0, ush* __restrict__ y1, ush* __restrict__ y2,
    ush* __restrict__ y3, float* __restrict__ part1)
{
  __shared__ __align__(16) ush smb[10*8*136];   // 21760B bf16 x tile
  __shared__ float red[4][14];
  const int hb = blockIdx.x, c = blockIdx.y, n = blockIdx.z, tid = threadIdx.x;
  const float* xc = x + ((size_t)(n*CC + c))*CS;
  #pragma unroll
  for (int i = 0; i < 10; ++i) {
    int idx = i*256 + tid;               // 2560 float4 = 10 rows * 256
    int row = idx >> 8, r4 = idx & 255;
    int w = r4 >> 1, zh = r4 & 1;
    int hin = hb*4 - 3 + row;
    float4 val = make_float4(0.f,0.f,0.f,0.f);
    if (hin >= 0 && hin < CH) val = *(const float4*)(xc + (size_t)hin*1024 + w*8 + zh*4);
    ush* base = smb + (row*8 + zh*4)*136 + 4 + w;
    base[0]   = f2bf(val.x);
    base[136] = f2bf(val.y);
    base[272] = f2bf(val.z);
    base[408] = f2bf(val.w);
  }
  for (int idx = tid; idx < 640; idx += 256) {   // zero w-halo: pw {0..3, 132..135}
    int row = idx >> 6, rem = idx & 63;
    int z = rem >> 3, col = rem & 7;
    int pw = (col < 4) ? col : (128 + col);
    smb[(row*8 + z)*136 + pw] = 0;
  }
  __syncthreads();

  const int wt = tid & 31, hh = (tid >> 5) & 3, zz = tid >> 7;
  f32x2 a0[4][2] = {}, a1[4][2] = {}, a2[4][2] = {}, a3[4][2] = {};
  if (zz == 0)
    conv_planes_bf<0>(smb, hh, wt, lk_w + c*147, dw5_w + c*75, dw3a_w + c*27, dw3b_w + c*27,
                      a0, a1, a2, a3);
  else
    conv_planes_bf<1>(smb, hh, wt, lk_w + c*147, dw5_w + c*75, dw3a_w + c*27, dw3b_w + c*27,
                      a0, a1, a2, a3);

  float s0=0,q0=0,s1=0,q1=0,s2=0,q2=0,s3=0,q3=0;
  acc_stats(a0, s0, q0); acc_stats(a1, s1, q1);
  acc_stats(a2, s2, q2); acc_stats(a3, s3, q3);
  float c01=0,c02=0,c03=0,c12=0,c13=0,c23=0;
  cross_stats(a0, a1, c01); cross_stats(a0, a2, c02); cross_stats(a0, a3, c03);
  cross_stats(a1, a2, c12); cross_stats(a1, a3, c13); cross_stats(a2, a3, c23);

  // ---- coalesced store via LDS exchange: 1 branch (8KB) per round ----
  char* exch = (char*)smb;           // smb dead; 8KB used
  const int hbase = hb*4;
  const size_t nbase = ((size_t)(n*CC + c))*CS;
  const int row_r = tid >> 6, j_r = tid & 63;    // row_r 0..3
  const int wt_s = j_r >> 1, p0 = (j_r & 1)*2;
  const int sxor = (wt_s & 7) << 3;
  #pragma unroll
  for (int rnd = 0; rnd < 4; ++rnd) {
    const f32x2 (&aa)[4][2] = (rnd == 0) ? a0 : (rnd == 1) ? a1 : (rnd == 2) ? a2 : a3;
    ush* yb = (rnd == 0) ? y0 : (rnd == 1) ? y1 : (rnd == 2) ? y2 : y3;
    __syncthreads();                 // previous round's reads (or conv reads) done
    {
      const int wbyte = hh*2048 + wt*64;         // 4 rows x 2KB = 8KB
      #pragma unroll
      for (int wp = 0; wp < 4; ++wp) {
        int swz = (wp*16 + zz*8) ^ ((wt & 7) << 3);
        *(uint2*)(exch + wbyte + swz) = packz(aa, wp);
      }
    }
    __syncthreads();
    {
      const char* src = exch + row_r*2048 + wt_s*64;
      uint2 e0 = *(const uint2*)(src + ((p0*16 + 0)  ^ sxor));
      uint2 e1 = *(const uint2*)(src + ((p0*16 + 8)  ^ sxor));
      uint2 e2 = *(const uint2*)(src + ((p0*16 + 16) ^ sxor));
      uint2 e3 = *(const uint2*)(src + ((p0*16 + 24) ^ sxor));
      ush* dst = yb + nbase + (size_t)(hbase + row_r)*1024 + j_r*16;
      *(uint4*)(dst)     = make_uint4(e0.x, e0.y, e1.x, e1.y);
      *(uint4*)(dst + 8) = make_uint4(e2.x, e2.y, e3.x, e3.y);
    }
  }

  float vals[14] = {s0,s1,s2,s3,q0,q1,q2,q3,c01,c02,c03,c12,c13,c23};
  #pragma unroll
  for (int jj = 0; jj < 14; ++jj) vals[jj] = wave_sum(vals[jj]);
  const int wid = tid >> 6, lane = tid & 63;
  if (lane == 0) {
    #pragma unroll
    for (int jj = 0; jj < 14; ++jj) red[wid][jj] = vals[jj];
  }
  __syncthreads();
  if (tid < 14) {
    float s = red[0][tid] + red[1][tid] + red[2][tid] + red[3][tid];
    part1[(((size_t)n*CC + c)*32 + hb)*16 + tid] = s;
  }
}

// ---------------------------------------------------------------------------
// K2: merged stats (32 hb slots): branch BN -> svec/T; analytic combined BN;
// SE -> ABuf
// ---------------------------------------------------------------------------
__global__ __launch_bounds__(512) void k_stats(
    const float* __restrict__ part1,
    const float* bn0_w, const float* bn0_b, const float* dbn1_w, const float* dbn1_b,
    const float* dbn2_w, const float* dbn2_b, const float* dbn3_w, const float* dbn3_b,
    const float* nrm_w, const float* nrm_b,
    const float* se_dw, const float* se_db, const float* se_uw, const float* se_ub,
    float* __restrict__ svec, float* __restrict__ Tbuf, float* __restrict__ ABuf)
{
  __shared__ float sA[4][128], tA[4][128], QA[4][128], S0A[4][128], SfA[4][128];
  __shared__ float pmA[2][128], hA[2][32], alA[128], beA[128];
  const int tid = threadIdx.x;
  {
    int c = tid >> 2, b = tid & 3;
    float s_f = 0.f, s_0 = 0.f, q = 0.f;
    for (int n = 0; n < 2; n++)
      for (int hb = 0; hb < 32; hb++) {
        const float* p = part1 + (((size_t)n*CC + c)*32 + hb)*16;
        float v = p[b];
        s_f += v; if (n == 0) s_0 += v;
        q += p[4 + b];
      }
    float mean = s_f * (1.f/262144.f);
    float var  = q * (1.f/262144.f) - mean*mean;
    float g, bb;
    if (b == 0)      { g = bn0_w[c];  bb = bn0_b[c];  }
    else if (b == 1) { g = dbn1_w[c]; bb = dbn1_b[c]; }
    else if (b == 2) { g = dbn2_w[c]; bb = dbn2_b[c]; }
    else             { g = dbn3_w[c]; bb = dbn3_b[c]; }
    float sc = g * rsqrtf(var + BNEPS);
    svec[c*4 + b] = sc;
    sA[b][c] = sc;
    tA[b][c] = bb - mean * sc;
    QA[b][c] = q; S0A[b][c] = s_0; SfA[b][c] = s_f;
  }
  __syncthreads();
  if (tid < 128) {
    int c = tid;
    float cr[6] = {0,0,0,0,0,0};
    for (int n = 0; n < 2; n++)
      for (int hb = 0; hb < 32; hb++) {
        const float* p = part1 + (((size_t)n*CC + c)*32 + hb)*16 + 8;
        #pragma unroll
        for (int k = 0; k < 6; k++) cr[k] += p[k];
      }
    float s0 = sA[0][c], s1 = sA[1][c], s2 = sA[2][c], s3 = sA[3][c];
    float T = tA[0][c] + tA[1][c] + tA[2][c] + tA[3][c];
    Tbuf[c] = T;
    float wf = s0*SfA[0][c] + s1*SfA[1][c] + s2*SfA[2][c] + s3*SfA[3][c];
    float w0 = s0*S0A[0][c] + s1*S0A[1][c] + s2*S0A[2][c] + s3*S0A[3][c];
    float sum_full = wf + 262144.f*T;
    float sumsq = s0*s0*QA[0][c] + s1*s1*QA[1][c] + s2*s2*QA[2][c] + s3*s3*QA[3][c]
                + 2.f*(s0*s1*cr[0] + s0*s2*cr[1] + s0*s3*cr[2]
                     + s1*s2*cr[3] + s1*s3*cr[4] + s2*s3*cr[5])
                + 2.f*T*wf + 262144.f*T*T;
    float m   = sum_full * (1.f/262144.f);
    float var = sumsq * (1.f/262144.f) - m*m;
    float inv = rsqrtf(var + BNEPS);
    float al = nrm_w[c]*inv;
    float be = nrm_b[c] - m*al;
    alA[c] = al; beA[c] = be;
    float sum_n0 = w0 + 131072.f*T;
    float sum_n1 = (wf - w0) + 131072.f*T;
    pmA[0][c] = (sum_n0*(1.f/131072.f) - m)*al + be;
    pmA[1][c] = (sum_n1*(1.f/131072.f) - m)*al + be;
  }
  __syncthreads();
  if (tid < 64) {
    int n = tid >> 5, i = tid & 31;
    float h = se_db[i];
    for (int c2 = 0; c2 < 128; c2++) h += pmA[n][c2]*se_dw[i*128 + c2];
    hA[n][i] = fmaxf(h, 0.f);
  }
  __syncthreads();
  if (tid < 256) {
    int n = tid >> 7, c = tid & 127;
    float sse = se_ub[c];
    #pragma unroll
    for (int i = 0; i < 32; i++) sse += hA[n][i]*se_uw[c*32 + i];
    ABuf[(n*128 + c)*2 + 0] = alA[c]*sse;
    ABuf[(n*128 + c)*2 + 1] = beA[c]*sse;
  }
}

// ---------------------------------------------------------------------------
// K5: fold A into w1 (bf16, [n][f][c]) and B into beta[n][f]
// ---------------------------------------------------------------------------
__global__ __launch_bounds__(512) void k_w1prep(
    const float* __restrict__ w1, const float* __restrict__ b1,
    const float* __restrict__ ABuf, ush* __restrict__ w1t, float* __restrict__ beta)
{
  const int n = blockIdx.x, tid = threadIdx.x;
  __shared__ float Asc[128], Bsc[128];
  if (tid < 128) { Asc[tid] = ABuf[(n*128 + tid)*2]; Bsc[tid] = ABuf[(n*128 + tid)*2 + 1]; }
  __syncthreads();
  for (int i = tid; i < 512*128; i += 512) {     // write-contiguous
    int f = i >> 7, cc = i & 127;
    w1t[((size_t)n*512 + f)*128 + cc] = f2bf(w1[cc*512 + f] * Asc[cc]);
  }
  {
    int f = tid;
    float s = b1[f];
    for (int cc = 0; cc < 128; cc++) s += Bsc[cc]*w1[cc*512 + f];
    beta[n*512 + f] = s;
  }
}

// ---------------------------------------------------------------------------
// K7: GEMM1, one block per (mt,n): combine A ONCE (granule-swizzle transpose
// via Bl scratch), keep in Al, loop ft=0..3 {stage B, MFMA, gelu, store}.
// ---------------------------------------------------------------------------
__global__ __launch_bounds__(256) void k_gemm1(
    const ush* __restrict__ y0, const ush* __restrict__ y1,
    const ush* __restrict__ y2, const ush* __restrict__ y3,
    const float* __restrict__ svec, const float* __restrict__ Tb,
    const ush* __restrict__ w1t, const float* __restrict__ beta,
    ush* __restrict__ tbuf, float* __restrict__ grnp)
{
  __shared__ __align__(16) ush Al[16384];
  __shared__ __align__(16) ush Bl[16384];
  __shared__ float grnl[256];
  const int l = blockIdx.x, tid = threadIdx.x;
  const int mt = l >> 1, n = l & 1;

  // step 1: combine branches into Bl (granule-swizzled transpose scratch)
  #pragma unroll
  for (int i = 0; i < 8; i++) {
    int g = i*256 + tid;
    int cc = g >> 4, s8 = g & 15;
    size_t off = ((size_t)(n*CC + cc))*CS + (size_t)mt*128 + s8*8;
    uint4 v0 = *(const uint4*)(y0 + off);
    uint4 v1 = *(const uint4*)(y1 + off);
    uint4 v2 = *(const uint4*)(y2 + off);
    uint4 v3 = *(const uint4*)(y3 + off);
    float4 sv = *(const float4*)(svec + cc*4);
    float Tc = Tb[cc];
    union { uint4 q; ush e[8]; } u0, u1, u2, u3, uo;
    u0.q = v0; u1.q = v1; u2.q = v2; u3.q = v3;
    #pragma unroll
    for (int j = 0; j < 8; j++) {
      float y = sv.x*bf2f(u0.e[j]) + sv.y*bf2f(u1.e[j])
              + sv.z*bf2f(u2.e[j]) + sv.w*bf2f(u3.e[j]) + Tc;
      uo.e[j] = f2bf(y);
    }
    #pragma unroll
    for (int j = 0; j < 8; j++) {
      int s_l = s8*8 + j;
      int gran = s_l*16 + ((cc >> 3) ^ (s8 & 7));
      Bl[gran*8 + (cc & 7)] = uo.e[j];
    }
  }
  __syncthreads();
  // step 2: read NSC 16B chunks out of the granule layout
  uint4 areg[8];
  #pragma unroll
  for (int i = 0; i < 8; i++) {
    int idx = i*256 + tid;
    int s_l = idx >> 4, gc = idx & 15;
    int gran = s_l*16 + (gc ^ ((s_l >> 3) & 7));
    areg[i] = *(const uint4*)&Bl[gran*8];
  }
  // step 3: place A MFMA-swizzled in Al (Bl reads done after barrier below)
  __syncthreads();
  #pragma unroll
  for (int i = 0; i < 8; i++) {
    int idx = i*256 + tid;
    int rr = idx >> 4, cg = idx & 15;
    *(uint4*)&Al[rr*128 + ((cg ^ (rr & 7))*8)] = areg[i];
  }

  const int wid = tid >> 6, lane = tid & 63;
  const int wm = wid >> 1, wn = wid & 1;
  const int lr = lane & 15, lk = lane >> 4;

  #pragma unroll 1
  for (int ft = 0; ft < 4; ++ft) {
    __syncthreads();          // Al visible (ft=0); prior Bl scatter-reads done
    const ush* Bb = w1t + ((size_t)n*512 + (size_t)ft*128) * 128;
    #pragma unroll
    for (int i = 0; i < 8; i++) {
      int idx = i*256 + tid;
      int rr = idx >> 4, cg = idx & 15;
      *(uint4*)&Bl[rr*128 + ((cg ^ (rr & 7))*8)] = *(const uint4*)(Bb + (size_t)idx*8);
    }
    __syncthreads();

    f32x4 acc[4][4] = {};
    #pragma unroll
    for (int kk = 0; kk < 4; kk++) {
      short8 af[4], bfr[4];
      #pragma unroll
      for (int mf = 0; mf < 4; mf++) {
        int row = wm*64 + mf*16 + lr;
        int cg = (kk*4 + lk) ^ (row & 7);
        af[mf] = *(const short8*)&Al[row*128 + cg*8];
      }
      #pragma unroll
      for (int nf = 0; nf < 4; nf++) {
        int row = wn*64 + nf*16 + lr;
        int cg = (kk*4 + lk) ^ (row & 7);
        bfr[nf] = *(const short8*)&Bl[row*128 + cg*8];
      }
      #pragma unroll
      for (int mf = 0; mf < 4; mf++)
        #pragma unroll
        for (int nf = 0; nf < 4; nf++)
          acc[mf][nf] = __builtin_amdgcn_mfma_f32_16x16x32_bf16(af[mf], bfr[nf], acc[mf][nf], 0, 0, 0);
    }

    float bt[4];
    #pragma unroll
    for (int nf = 0; nf < 4; nf++) bt[nf] = beta[n*512 + ft*128 + wn*64 + nf*16 + lr];
    float sq[4] = {0.f,0.f,0.f,0.f};
    #pragma unroll
    for (int mf = 0; mf < 4; mf++)
      #pragma unroll
      for (int nf = 0; nf < 4; nf++)
        #pragma unroll
        for (int rg = 0; rg < 4; rg++) {
          float g = gelu_tanh(acc[mf][nf][rg] + bt[nf]);
          sq[nf] += g*g;
          acc[mf][nf][rg] = g;
        }
    __syncthreads();          // MFMA reads of Bl done
    #pragma unroll
    for (int nf = 0; nf < 4; nf++) {
      float v = sq[nf];
      v += __shfl_xor(v, 16); v += __shfl_xor(v, 32);
      if (lane < 16) grnl[(wn*64 + nf*16 + lane)*2 + wm] = v;
    }
    #pragma unroll
    for (int mf = 0; mf < 4; mf++)
      #pragma unroll
      for (int nf = 0; nf < 4; nf++)
        #pragma unroll
        for (int rg = 0; rg < 4; rg++) {
          int ml = wm*64 + mf*16 + lk*4 + rg;
          int fl = wn*64 + nf*16 + lr;
          Bl[ml*128 + (fl ^ (((ml >> 2) & 3) << 4))] = f2bf(acc[mf][nf][rg]);
        }
    __syncthreads();
    #pragma unroll
    for (int i = 0; i < 8; i++) {
      int idx = i*256 + tid;
      int m = idx >> 4, gc = idx & 15;
      uint4 v = *(const uint4*)&Bl[m*128 + ((gc ^ (((m >> 2) & 3) << 1))*8)];
      *(uint4*)(tbuf + ((size_t)n*CS + (size_t)mt*128 + m)*512 + ft*128 + gc*8) = v;
    }
    if (tid < 128) grnp[(size_t)mt*1024 + n*512 + ft*128 + tid] = grnl[tid*2] + grnl[tid*2+1];
  }
}

// K8a: GRN partial reduce over mt (64 blocks)
__global__ __launch_bounds__(256) void k_grn1(
    const float* __restrict__ grnp, float* __restrict__ gpart)
{
  const int j = blockIdx.x, tid = threadIdx.x;
  float acc[4] = {0.f, 0.f, 0.f, 0.f};
  for (int i = 0; i < 16; ++i) {
    const float* p = grnp + (size_t)(j*16 + i)*1024;
    #pragma unroll
    for (int ch = 0; ch < 4; ++ch) acc[ch] += p[ch*256 + tid];
  }
  #pragma unroll
  for (int ch = 0; ch < 4; ++ch) gpart[(size_t)j*1024 + ch*256 + tid] = acc[ch];
}

// K8b: GRN final: Gx -> Nx -> a[n][f] = grn_g*Nx + 1
__global__ __launch_bounds__(1024) void k_grn2(
    const float* __restrict__ gpart, const float* __restrict__ grn_g, float* __restrict__ aBuf)
{
  __shared__ float wsum[16], gm[2];
  const int tid = threadIdx.x;
  float s = 0.f;
  for (int j = 0; j < 64; ++j) s += gpart[(size_t)j*1024 + tid];
  float Gx = sqrtf(s);
  float v = wave_sum(Gx);
  if ((tid & 63) == 0) wsum[tid >> 6] = v;
  __syncthreads();
  if (tid < 2) {
    float m = 0.f;
    #pragma unroll
    for (int w2 = 0; w2 < 8; w2++) m += wsum[tid*8 + w2];
    gm[tid] = m * (1.f/512.f) + 1e-6f;
  }
  __syncthreads();
  int n = tid >> 9, f = tid & 511;
  aBuf[tid] = grn_g[f] * (Gx / gm[n]) + 1.f;
}

// K9: w2t[n][co][f] = w2[f][co]*a[n][f]  (bf16)  + cvec (n==0 block)
__global__ __launch_bounds__(512) void k_w2prep(
    const float* __restrict__ w2, const float* __restrict__ aBuf,
    const float* __restrict__ grn_b, ush* __restrict__ w2t, float* __restrict__ cvec)
{
  const int n = blockIdx.x, tid = threadIdx.x;
  for (int i = tid; i < 128*512; i += 512) {     // write-contiguous
    int co = i >> 9, f = i & 511;
    w2t[((size_t)n*128 + co)*512 + f] = f2bf(w2[(size_t)f*128 + co] * aBuf[n*512 + f]);
  }
  if (n == 0) {
    __shared__ float cs[4][128];
    int co = tid & 127, qh = tid >> 7;
    float s = 0.f;
    for (int f = qh*128; f < qh*128 + 128; ++f) s += grn_b[f]*w2[(size_t)f*128 + co];
    cs[qh][co] = s;
    __syncthreads();
    if (tid < 128) cvec[tid] = cs[0][tid] + cs[1][tid] + cs[2][tid] + cs[3][tid];
  }
}

// ---------------------------------------------------------------------------
// K11: GEMM2  u (NCS layout) = t @ w2t_n^T + cvec, bf16 out + post-BN partials
// ---------------------------------------------------------------------------
__global__ __launch_bounds__(256) void k_gemm2(
    const ush* __restrict__ tbuf, const ush* __restrict__ w2t,
    const float* __restrict__ cvec, ush* __restrict__ u, float* __restrict__ upart)
{
  __shared__ __align__(16) ush Al[16384];
  __shared__ __align__(16) ush Bl[16384];
  const int mt = blockIdx.x, n = blockIdx.y, tid = threadIdx.x;
  const int wid = tid >> 6, lane = tid & 63;
  const int wm = wid >> 1, wn = wid & 1;
  const int lr = lane & 15, lk = lane >> 4;
  f32x4 acc[4][4] = {};
  #pragma unroll 1
  for (int kb = 0; kb < 4; kb++) {
    if (kb) __syncthreads();
    #pragma unroll
    for (int i = 0; i < 8; i++) {
      int g = i*256 + tid;
      int rr = g >> 4, cg = g & 15;
      *(uint4*)&Al[rr*128 + ((cg ^ (rr & 7))*8)] =
        *(const uint4*)(tbuf + ((size_t)n*CS + (size_t)mt*128 + rr)*512 + kb*128 + cg*8);
      *(uint4*)&Bl[rr*128 + ((cg ^ (rr & 7))*8)] =
        *(const uint4*)(w2t + ((size_t)n*128 + rr)*512 + kb*128 + cg*8);
    }
    __syncthreads();
    #pragma unroll
    for (int kk = 0; kk < 4; kk++) {
      short8 af[4], bfr[4];
      #pragma unroll
      for (int mf = 0; mf < 4; mf++) {
        int row = wm*64 + mf*16 + lr;
        int cg = (kk*4 + lk) ^ (row & 7);
        af[mf] = *(const short8*)&Al[row*128 + cg*8];
      }
      #pragma unroll
      for (int nf = 0; nf < 4; nf++) {
        int row = wn*64 + nf*16 + lr;
        int cg = (kk*4 + lk) ^ (row & 7);
        bfr[nf] = *(const short8*)&Bl[row*128 + cg*8];
      }
      #pragma unroll
      for (int mf = 0; mf < 4; mf++)
        #pragma unroll
        for (int nf = 0; nf < 4; nf++)
          acc[mf][nf] = __builtin_amdgcn_mfma_f32_16x16x32_bf16(af[mf], bfr[nf], acc[mf][nf], 0, 0, 0);
    }
  }
  float cv[4];
  #pragma unroll
  for (int nf = 0; nf < 4; nf++) cv[nf] = cvec[wn*64 + nf*16 + lr];
  float su[4] = {0,0,0,0}, sq[4] = {0,0,0,0};
  #pragma unroll
  for (int mf = 0; mf < 4; mf++)
    #pragma unroll
    for (int nf = 0; nf < 4; nf++)
      #pragma unroll
      for (int rg = 0; rg < 4; rg++) {
        float v = acc[mf][nf][rg] + cv[nf];
        su[nf] += v; sq[nf] += v*v;
        acc[mf][nf][rg] = v;
      }
  __syncthreads();
  float* stl = (float*)Al;
  #pragma unroll
  for (int nf = 0; nf < 4; nf++) {
    float a = su[nf]; a += __shfl_xor(a, 16); a += __shfl_xor(a, 32);
    float b = sq[nf]; b += __shfl_xor(b, 16); b += __shfl_xor(b, 32);
    if (lane < 16) {
      stl[((wn*64 + nf*16 + lane)*2 + wm)*2 + 0] = a;
      stl[((wn*64 + nf*16 + lane)*2 + wm)*2 + 1] = b;
    }
  }
  // transposed scatter: Bl row = c index (fl), col = s index (ml)
  #pragma unroll
  for (int mf = 0; mf < 4; mf++)
    #pragma unroll
    for (int nf = 0; nf < 4; nf++)
      #pragma unroll
      for (int rg = 0; rg < 4; rg++) {
        int ml = wm*64 + mf*16 + lk*4 + rg;
        int fl = wn*64 + nf*16 + lr;
        Bl[fl*128 + (ml ^ (((fl >> 2) & 3) << 4))] = f2bf(acc[mf][nf][rg]);
      }
  __syncthreads();
  #pragma unroll
  for (int i = 0; i < 8; i++) {
    int idx = i*256 + tid;
    int cr = idx >> 4, gm = idx & 15;
    uint4 v = *(const uint4*)&Bl[cr*128 + ((gm ^ (((cr >> 2) & 3) << 1))*8)];
    *(uint4*)(u + ((size_t)(n*CC + cr))*CS + (size_t)mt*128 + gm*8) = v;
  }
  if (tid < 128) {
    float s = stl[(tid*2 + 0)*2 + 0] + stl[(tid*2 + 1)*2 + 0];
    float q = stl[(tid*2 + 0)*2 + 1] + stl[(tid*2 + 1)*2 + 1];
    upart[((size_t)(n*1024 + mt)*128 + tid)*2 + 0] = s;
    upart[((size_t)(n*1024 + mt)*128 + tid)*2 + 1] = q;
  }
}

// K12: post-BN stats -> P,Q per channel
__global__ __launch_bounds__(256) void k_pbn(
    const float* __restrict__ upart, const float* pbn_w, const float* pbn_b,
    const float* ls_g, float* __restrict__ PQ)
{
  __shared__ float rs[4], rq[4];
  const int c = blockIdx.x, tid = threadIdx.x;
  float s = 0.f, q = 0.f;
  for (int mtg = tid; mtg < 2048; mtg += 256) {
    s += upart[((size_t)mtg*128 + c)*2 + 0];
    q += upart[((size_t)mtg*128 + c)*2 + 1];
  }
  s = wave_sum(s); q = wave_sum(q);
  if ((tid & 63) == 0) { rs[tid >> 6] = s; rq[tid >> 6] = q; }
  __syncthreads();
  if (tid == 0) {
    float S = rs[0]+rs[1]+rs[2]+rs[3];
    float Qq = rq[0]+rq[1]+rq[2]+rq[3];
    float m = S*(1.f/262144.f);
    float var = Qq*(1.f/262144.f) - m*m;
    float inv = rsqrtf(var + BNEPS);
    PQ[c*2 + 0] = ls_g[c]*pbn_w[c]*inv;
    PQ[c*2 + 1] = ls_g[c]*(pbn_b[c] - m*inv*pbn_w[c]);
  }
}

// K13: out[n,c,s] = x + u_ncs*P[c] + Q[c]  — the ONLY writer of d_out
__global__ __launch_bounds__(256) void k_final(
    const ush* __restrict__ u, const float* __restrict__ x,
    const float* __restrict__ PQ, float* __restrict__ out)
{
  size_t e = ((size_t)blockIdx.x*256 + threadIdx.x)*4;
  int c = (int)((e >> 17) & 127);
  float P = PQ[c*2], Q = PQ[c*2 + 1];
  uint2 uv = *(const uint2*)(u + e);
  float4 xv = *(const float4*)(x + e);
  float4 o;
  o.x = fmaf(bf2f((ush)(uv.x & 0xffff)), P, xv.x + Q);
  o.y = fmaf(bf2f((ush)(uv.x >> 16)),   P, xv.y + Q);
  o.z = fmaf(bf2f((ush)(uv.y & 0xffff)), P, xv.z + Q);
  o.w = fmaf(bf2f((ush)(uv.y >> 16)),   P, xv.w + Q);
  *(float4*)(out + e) = o;
}

// ---------------------------------------------------------------------------
extern "C" void kernel_launch(void* const* d_in, const int* in_sizes, int n_in,
                              void* d_out, int out_size, void* d_ws, size_t ws_size,
                              hipStream_t stream)
{
  (void)in_sizes; (void)n_in; (void)out_size; (void)ws_size;
  const float* x      = (const float*)d_in[0];
  const float* lk_w   = (const float*)d_in[1];
  const float* bn0_w  = (const float*)d_in[2];
  const float* bn0_b  = (const float*)d_in[3];
  const float* dw5_w  = (const float*)d_in[4];
  const float* dbn1_w = (const float*)d_in[5];
  const float* dbn1_b = (const float*)d_in[6];
  const float* dw3a_w = (const float*)d_in[7];
  const float* dbn2_w = (const float*)d_in[8];
  const float* dbn2_b = (const float*)d_in[9];
  const float* dw3b_w = (const float*)d_in[10];
  const float* dbn3_w = (const float*)d_in[11];
  const float* dbn3_b = (const float*)d_in[12];
  const float* nrm_w  = (const float*)d_in[13];
  const float* nrm_b  = (const float*)d_in[14];
  const float* se_dw  = (const float*)d_in[15];
  const float* se_db  = (const float*)d_in[16];
  const float* se_uw  = (const float*)d_in[17];
  const float* se_ub  = (const float*)d_in[18];
  const float* w1     = (const float*)d_in[19];
  const float* b1     = (const float*)d_in[20];
  const float* grn_g  = (const float*)d_in[21];
  const float* grn_b  = (const float*)d_in[22];
  const float* w2     = (const float*)d_in[23];
  const float* pbn_w  = (const float*)d_in[24];
  const float* pbn_b  = (const float*)d_in[25];
  const float* ls_g   = (const float*)d_in[26];

  char* w = (char*)d_ws;
  size_t cur = 0;
  auto take = [&](size_t b) { size_t r = cur; cur += (b + 255) & ~(size_t)255; return r; };
  ush*   tbuf  = (ush*)  (w + take((size_t)2*CS*512*2));   // 268.4MB; y0..y3 alias (exact fit)
  ush*   ycl_u = (ush*)  (w + take((size_t)2*CS*128*2));   // 67.1MB; u
  float* partU = (float*)(w + take((size_t)2*128*32*16*4));// part1: 2*128*32 slots x16
  float* svec  = (float*)(w + take(128*4*4));
  float* TbufA = (float*)(w + take(128*4));
  float* ABuf  = (float*)(w + take(2*128*2*4));
  ush*   w1t   = (ush*)  (w + take(2*512*128*2));
  float* beta  = (float*)(w + take(2*512*4));
  float* grnpU = (float*)(w + take((size_t)1024*1024*4));  // grnp then upart
  float* gpart = (float*)(w + take((size_t)64*1024*4));
  float* aBuf  = (float*)(w + take(2*512*4));
  ush*   w2t   = (ush*)  (w + take(2*128*512*2));
  float* cvec  = (float*)(w + take(128*4));
  float* PQ    = (float*)(w + take(128*2*4));

  const size_t YSZ = (size_t)2*CC*CS;         // 33.5M ush per branch buffer
  ush*   y0    = tbuf;
  ush*   y1    = tbuf + YSZ;
  ush*   y2    = tbuf + 2*YSZ;
  ush*   y3    = tbuf + 3*YSZ;
  ush*   u_buf = ycl_u;
  float* part1 = partU;
  float* grnp  = grnpU;
  float* upart = grnpU;
  float* outp  = (float*)d_out;

  k_conv4<<<dim3(32,128,2), 256, 0, stream>>>(x, lk_w, dw5_w, dw3a_w, dw3b_w,
                                              y0, y1, y2, y3, part1);
  k_stats<<<1, 512, 0, stream>>>(part1, bn0_w, bn0_b, dbn1_w, dbn1_b,
                                 dbn2_w, dbn2_b, dbn3_w, dbn3_b,
                                 nrm_w, nrm_b, se_dw, se_db, se_uw, se_ub,
                                 svec, TbufA, ABuf);
  k_w1prep<<<2, 512, 0, stream>>>(w1, b1, ABuf, w1t, beta);
  k_gemm1<<<2048, 256, 0, stream>>>(y0, y1, y2, y3, svec, TbufA, w1t, beta, tbuf, grnp);
  k_grn1<<<64, 256, 0, stream>>>(grnp, gpart);
  k_grn2<<<1, 1024, 0, stream>>>(gpart, grn_g, aBuf);
  k_w2prep<<<2, 512, 0, stream>>>(w2, aBuf, grn_b, w2t, cvec);
  k_gemm2<<<dim3(1024,2), 256, 0, stream>>>(tbuf, w2t, cvec, u_buf, upart);
  k_pbn<<<128, 256, 0, stream>>>(upart, pbn_w, pbn_b, ls_g, PQ);
  k_final<<<32768, 256, 0, stream>>>(u_buf, x, PQ, outp);
}